// Round 1
// baseline (27283.197 us; speedup 1.0000x reference)
//
#include <hip/hip_runtime.h>
#include <math.h>

#define BB 2
#define SDOC 2048
#define SSUM 1024
#define HD 768
#define NHEAD 12
#define DHEAD 64
#define FFD 3072
#define NLAYER 6
#define PD 256
#define NSPAN 32
#define WINSZ 256

// ---------------- block reductions (blockDim == 256) ----------------
__device__ __forceinline__ float block_reduce_sum(float v) {
  __shared__ float sbuf[256];
  sbuf[threadIdx.x] = v;
  __syncthreads();
  for (int i = 128; i > 0; i >>= 1) {
    if ((int)threadIdx.x < i) sbuf[threadIdx.x] += sbuf[threadIdx.x + i];
    __syncthreads();
  }
  float r = sbuf[0];
  __syncthreads();
  return r;
}

__device__ __forceinline__ float block_reduce_max(float v) {
  __shared__ float mbuf[256];
  mbuf[threadIdx.x] = v;
  __syncthreads();
  for (int i = 128; i > 0; i >>= 1) {
    if ((int)threadIdx.x < i) mbuf[threadIdx.x] = fmaxf(mbuf[threadIdx.x], mbuf[threadIdx.x + i]);
    __syncthreads();
  }
  float r = mbuf[0];
  __syncthreads();
  return r;
}

// ---------------- embedding + LayerNorm (one block per row, H=768) ----------------
__global__ __launch_bounds__(256) void embed_ln_kernel(
    const int* __restrict__ ids, const float* __restrict__ we, const float* __restrict__ pe,
    const float* __restrict__ g, const float* __restrict__ bt, float* __restrict__ xout, int S) {
  int row = blockIdx.x;
  int s = row % S;
  int id = ids[row];
  int tid = threadIdx.x;
  float vals[3];
  float sum = 0.f;
#pragma unroll
  for (int i = 0; i < 3; i++) {
    int h = tid + i * 256;
    float t = we[(size_t)id * HD + h] + pe[(size_t)s * HD + h];
    vals[i] = t;
    sum += t;
  }
  float mean = block_reduce_sum(sum) * (1.f / HD);
  float vs = 0.f;
#pragma unroll
  for (int i = 0; i < 3; i++) { float d = vals[i] - mean; vs += d * d; }
  float var = block_reduce_sum(vs) * (1.f / HD);
  float inv = rsqrtf(var + 1e-5f);
#pragma unroll
  for (int i = 0; i < 3; i++) {
    int h = tid + i * 256;
    xout[(size_t)row * HD + h] = (vals[i] - mean) * inv * g[h] + bt[h];
  }
}

// ---------------- LayerNorm (optional residual), one block per row ----------------
__global__ __launch_bounds__(256) void ln_kernel(
    const float* __restrict__ a, const float* __restrict__ res,
    const float* __restrict__ g, const float* __restrict__ bt, float* __restrict__ out) {
  int row = blockIdx.x;
  int tid = threadIdx.x;
  const float* ar = a + (size_t)row * HD;
  const float* rr = res ? res + (size_t)row * HD : nullptr;
  float vals[3];
  float sum = 0.f;
#pragma unroll
  for (int i = 0; i < 3; i++) {
    int h = tid + i * 256;
    float t = ar[h] + (rr ? rr[h] : 0.f);
    vals[i] = t;
    sum += t;
  }
  float mean = block_reduce_sum(sum) * (1.f / HD);
  float vs = 0.f;
#pragma unroll
  for (int i = 0; i < 3; i++) { float d = vals[i] - mean; vs += d * d; }
  float var = block_reduce_sum(vs) * (1.f / HD);
  float inv = rsqrtf(var + 1e-5f);
#pragma unroll
  for (int i = 0; i < 3; i++) {
    int h = tid + i * 256;
    out[(size_t)row * HD + h] = (vals[i] - mean) * inv * g[h] + bt[h];
  }
}

// ---------------- fp32 tiled GEMM: C = A(M,K) @ W(K,N) + bias, act=1 -> exact GELU ----
#define GTM 64
#define GTN 64
#define GTK 16
__global__ __launch_bounds__(256) void gemm_f32(
    const float* __restrict__ A, const float* __restrict__ W, const float* __restrict__ bias,
    float* __restrict__ C, int M, int N, int K, int act) {
  __shared__ float As[GTK][GTM + 1];
  __shared__ float Bs[GTK][GTN + 1];
  int bm = blockIdx.y * GTM;
  int bn = blockIdx.x * GTN;
  int tid = threadIdx.x;
  int tx = tid & 15, ty = tid >> 4;
  float acc[4][4] = {{0.f}};
  for (int k0 = 0; k0 < K; k0 += GTK) {
    for (int e = tid; e < GTM * GTK; e += 256) {
      int m = e >> 4, kk = e & 15;
      int gm = bm + m;
      As[kk][m] = (gm < M) ? A[(size_t)gm * K + k0 + kk] : 0.f;
    }
    for (int e = tid; e < GTK * GTN; e += 256) {
      int kk = e >> 6, n = e & 63;
      Bs[kk][n] = W[(size_t)(k0 + kk) * N + bn + n];
    }
    __syncthreads();
#pragma unroll
    for (int kk = 0; kk < GTK; kk++) {
      float av[4], bv[4];
#pragma unroll
      for (int i = 0; i < 4; i++) av[i] = As[kk][ty * 4 + i];
#pragma unroll
      for (int j = 0; j < 4; j++) bv[j] = Bs[kk][tx * 4 + j];
#pragma unroll
      for (int i = 0; i < 4; i++)
#pragma unroll
        for (int j = 0; j < 4; j++) acc[i][j] += av[i] * bv[j];
    }
    __syncthreads();
  }
#pragma unroll
  for (int i = 0; i < 4; i++) {
    int gm = bm + ty * 4 + i;
    if (gm >= M) continue;
#pragma unroll
    for (int j = 0; j < 4; j++) {
      int gn = bn + tx * 4 + j;
      float v = acc[i][j] + bias[gn];
      if (act == 1) v = 0.5f * v * (1.f + erff(v * 0.70710678118654752f));
      C[(size_t)gm * N + gn] = v;
    }
  }
}

// ---------------- sliding-window attention ----------------
// block = (qtile of 16 queries, head, batch). Each query attends keys |kp-p|<=256.
#define QT 16
#define KSLOTS 576  // 9 tiles of 64 >= 16+512 span
__global__ __launch_bounds__(256) void attn_kernel(
    const float* __restrict__ Qg, const float* __restrict__ Kg, const float* __restrict__ Vg,
    const int* __restrict__ amask, float* __restrict__ Og, int S) {
  __shared__ float sc[QT][KSLOTS];     // 36864 B
  __shared__ float Qs[QT][DHEAD];      // 4096 B
  __shared__ float Ks[64][DHEAD + 1];  // 16640 B
  int b = blockIdx.z, hd = blockIdx.y;
  int p0 = blockIdx.x * QT;
  int tid = threadIdx.x;
  int kstart = p0 - WINSZ;

  for (int e = tid; e < QT * DHEAD; e += 256) {
    int q = e >> 6, d = e & 63;
    Qs[q][d] = Qg[((size_t)(b * S + p0 + q)) * HD + hd * DHEAD + d] * 0.125f;  // 1/sqrt(64)
  }
  // scores
  for (int t = 0; t < 9; t++) {
    __syncthreads();
    for (int e = tid; e < 64 * DHEAD; e += 256) {
      int k = e >> 6, d = e & 63;
      int kp = kstart + t * 64 + k;
      Ks[k][d] = (kp >= 0 && kp < S) ? Kg[((size_t)(b * S + kp)) * HD + hd * DHEAD + d] : 0.f;
    }
    __syncthreads();
    for (int e = tid; e < QT * 64; e += 256) {
      int q = e >> 6, k = e & 63;
      float acc = 0.f;
#pragma unroll
      for (int d = 0; d < DHEAD; d++) acc += Qs[q][d] * Ks[k][d];
      sc[q][t * 64 + k] = acc;
    }
  }
  __syncthreads();
  // masked softmax per query row (16 lanes per row)
  {
    int q = tid >> 4, l16 = tid & 15;
    float mx = -1e30f;
    for (int j = l16; j < KSLOTS; j += 16) {
      int kp = kstart + j;
      bool valid = (kp >= 0) && (kp < S) && (j >= q) && (j <= q + 2 * WINSZ) &&
                   (amask[b * S + kp] != 0);
      float v = valid ? sc[q][j] : -1e9f;
      sc[q][j] = v;
      mx = fmaxf(mx, v);
    }
    for (int off = 8; off > 0; off >>= 1) mx = fmaxf(mx, __shfl_down(mx, off, 16));
    mx = __shfl(mx, 0, 16);
    float sum = 0.f;
    for (int j = l16; j < KSLOTS; j += 16) {
      float e = expf(sc[q][j] - mx);
      sc[q][j] = e;
      sum += e;
    }
    for (int off = 8; off > 0; off >>= 1) sum += __shfl_down(sum, off, 16);
    sum = __shfl(sum, 0, 16);
    float inv = 1.f / sum;
    for (int j = l16; j < KSLOTS; j += 16) sc[q][j] *= inv;
  }
  // PV
  float outv[4] = {0.f, 0.f, 0.f, 0.f};
  for (int t = 0; t < 9; t++) {
    __syncthreads();
    for (int e = tid; e < 64 * DHEAD; e += 256) {
      int k = e >> 6, d = e & 63;
      int kp = kstart + t * 64 + k;
      Ks[k][d] = (kp >= 0 && kp < S) ? Vg[((size_t)(b * S + kp)) * HD + hd * DHEAD + d] : 0.f;
    }
    __syncthreads();
#pragma unroll
    for (int i = 0; i < 4; i++) {
      int e = tid + i * 256;
      int q = e >> 6, d = e & 63;
      float a = 0.f;
#pragma unroll
      for (int k = 0; k < 64; k++) a += sc[q][t * 64 + k] * Ks[k][d];
      outv[i] += a;
    }
  }
#pragma unroll
  for (int i = 0; i < 4; i++) {
    int e = tid + i * 256;
    int q = e >> 6, d = e & 63;
    Og[((size_t)(b * S + p0 + q)) * HD + hd * DHEAD + d] = outv[i];
  }
}

// ---------------- span pooling: one block per span ----------------
__global__ __launch_bounds__(256) void pool_kernel(
    const float* __restrict__ seq, const int* __restrict__ spans, const int* __restrict__ sidx,
    const float* __restrict__ pw, float* __restrict__ emb, int S) {
  __shared__ float sc[2048];
  int ns = blockIdx.x;
  int bi = sidx[ns];
  const float* xb = seq + (size_t)bi * S * HD;
  int tid = threadIdx.x;
  for (int s = tid; s < S; s += 256) {
    float d = 0.f;
    const float* row = xb + (size_t)s * HD;
    for (int h = 0; h < HD; h++) d += row[h] * pw[h];
    d = fminf(fmaxf(d, -100.f), 100.f);
    sc[s] = (spans[ns * S + s] == 1) ? d : -1e9f;
  }
  __syncthreads();
  float mx = -1e30f;
  for (int s = tid; s < S; s += 256) mx = fmaxf(mx, sc[s]);
  mx = block_reduce_max(mx);
  float sum = 0.f;
  for (int s = tid; s < S; s += 256) {
    float e = expf(sc[s] - mx);
    sc[s] = e;
    sum += e;
  }
  sum = block_reduce_sum(sum);
  float inv = 1.f / sum;
  for (int h = tid; h < HD; h += 256) {
    float acc = 0.f;
    for (int s = 0; s < S; s++) acc += sc[s] * xb[(size_t)s * HD + h];
    emb[ns * HD + h] = acc * inv;
  }
}

// ---------------- final L2 normalize, one block per span (P=256=blockDim) -----------
__global__ __launch_bounds__(256) void norm_out_kernel(
    const float* __restrict__ proj, float* __restrict__ out) {
  int ns = blockIdx.x;
  float v = proj[ns * PD + threadIdx.x];
  float ss = block_reduce_sum(v * v);
  float n = fmaxf(sqrtf(ss), 1e-12f);
  out[ns * PD + threadIdx.x] = v / n;
}

// ---------------- host side ----------------
static void launch_gemm(const float* A, const float* W, const float* bias, float* C,
                        int M, int N, int K, int act, hipStream_t stream) {
  dim3 grid(N / GTN, (M + GTM - 1) / GTM);
  gemm_f32<<<grid, 256, 0, stream>>>(A, W, bias, C, M, N, K, act);
}

extern "C" void kernel_launch(void* const* d_in, const int* in_sizes, int n_in,
                              void* d_out, int out_size, void* d_ws, size_t ws_size,
                              hipStream_t stream) {
  const int* doc_ids   = (const int*)d_in[0];
  const int* doc_am    = (const int*)d_in[1];
  const int* sum_ids   = (const int*)d_in[2];
  const int* sum_am    = (const int*)d_in[3];
  const int* og_spans  = (const int*)d_in[4];
  const int* llm_spans = (const int*)d_in[5];
  const int* sidx      = (const int*)d_in[6];
  const float* word_emb = (const float*)d_in[7];
  const float* pos_emb  = (const float*)d_in[8];
  const float* emb_g = (const float*)d_in[9];
  const float* emb_b = (const float*)d_in[10];
  const float* Wq = (const float*)d_in[11];
  const float* bq = (const float*)d_in[12];
  const float* Wk = (const float*)d_in[13];
  const float* bk = (const float*)d_in[14];
  const float* Wv = (const float*)d_in[15];
  const float* bv = (const float*)d_in[16];
  const float* Wo = (const float*)d_in[17];
  const float* bo = (const float*)d_in[18];
  const float* lnag = (const float*)d_in[19];
  const float* lnab = (const float*)d_in[20];
  const float* Wf1 = (const float*)d_in[21];
  const float* bf1 = (const float*)d_in[22];
  const float* Wf2 = (const float*)d_in[23];
  const float* bf2 = (const float*)d_in[24];
  const float* lnfg = (const float*)d_in[25];
  const float* lnfb = (const float*)d_in[26];
  const float* pool_w = (const float*)d_in[27];
  const float* pj_g1 = (const float*)d_in[28];
  const float* pj_b1 = (const float*)d_in[29];
  const float* pj_W1 = (const float*)d_in[30];
  const float* pj_c1 = (const float*)d_in[31];
  const float* pj_g2 = (const float*)d_in[32];
  const float* pj_b2 = (const float*)d_in[33];
  const float* pj_W2 = (const float*)d_in[34];
  const float* pj_c2 = (const float*)d_in[35];
  float* out = (float*)d_out;
  float* ws = (float*)d_ws;

  // workspace layout (floats). total ~26.8M floats ~= 102 MiB
  float* xd = ws;                                // BB*SDOC*HD doc activations / doc_out
  float* xs = xd + (size_t)BB * SDOC * HD;       // BB*SSUM*HD summary activations
  float* qb = xs + (size_t)BB * SSUM * HD;       // BB*SDOC*HD
  float* kb = qb + (size_t)BB * SDOC * HD;       // BB*SDOC*HD
  float* vb = kb + (size_t)BB * SDOC * HD;       // BB*SDOC*HD
  float* hb = vb + (size_t)BB * SDOC * HD;       // BB*SDOC*FFD (FFN hidden; aliased attn out)
  float* ab = hb;                                // attn out aliases hb (dead before FFN1 write)
  float* emb  = hb + (size_t)BB * SDOC * FFD;    // NSPAN*HD
  float* h2   = emb + NSPAN * HD;                // NSPAN*HD
  float* proj = h2 + NSPAN * HD;                 // NSPAN*PD

  for (int pass = 0; pass < 2; pass++) {
    int S = (pass == 0) ? SDOC : SSUM;
    const int* ids = (pass == 0) ? doc_ids : sum_ids;
    const int* am  = (pass == 0) ? doc_am : sum_am;
    float* x = (pass == 0) ? xd : xs;
    int M = BB * S;
    embed_ln_kernel<<<M, 256, 0, stream>>>(ids, word_emb, pos_emb, emb_g, emb_b, x, S);
    for (int l = 0; l < NLAYER; l++) {
      const float* wq = Wq + (size_t)l * HD * HD;
      const float* wk = Wk + (size_t)l * HD * HD;
      const float* wv = Wv + (size_t)l * HD * HD;
      const float* wo = Wo + (size_t)l * HD * HD;
      launch_gemm(x, wq, bq + l * HD, qb, M, HD, HD, 0, stream);
      launch_gemm(x, wk, bk + l * HD, kb, M, HD, HD, 0, stream);
      launch_gemm(x, wv, bv + l * HD, vb, M, HD, HD, 0, stream);
      attn_kernel<<<dim3(S / QT, NHEAD, BB), 256, 0, stream>>>(qb, kb, vb, am, ab, S);
      launch_gemm(ab, wo, bo + l * HD, kb, M, HD, HD, 0, stream);  // kb = attn proj (K dead)
      ln_kernel<<<M, 256, 0, stream>>>(kb, x, lnag + l * HD, lnab + l * HD, x);
      launch_gemm(x, Wf1 + (size_t)l * HD * FFD, bf1 + l * FFD, hb, M, FFD, HD, 1, stream);
      launch_gemm(hb, Wf2 + (size_t)l * FFD * HD, bf2 + l * HD, qb, M, HD, FFD, 0, stream);
      ln_kernel<<<M, 256, 0, stream>>>(qb, x, lnfg + l * HD, lnfb + l * HD, x);
    }
  }

  for (int pass = 0; pass < 2; pass++) {
    const float* seq = (pass == 0) ? xd : xs;
    const int* spans = (pass == 0) ? og_spans : llm_spans;
    int S = (pass == 0) ? SDOC : SSUM;
    pool_kernel<<<NSPAN, 256, 0, stream>>>(seq, spans, sidx, pool_w, emb, S);
    ln_kernel<<<NSPAN, 256, 0, stream>>>(emb, nullptr, pj_g1, pj_b1, h2);
    launch_gemm(h2, pj_W1, pj_c1, emb, NSPAN, HD, HD, 1, stream);  // gelu
    ln_kernel<<<NSPAN, 256, 0, stream>>>(emb, nullptr, pj_g2, pj_b2, h2);
    launch_gemm(h2, pj_W2, pj_c2, proj, NSPAN, PD, HD, 0, stream);
    norm_out_kernel<<<NSPAN, 256, 0, stream>>>(proj, out + pass * NSPAN * PD);
  }
}

// Round 2
// 11491.617 us; speedup vs baseline: 2.3742x; 2.3742x over previous
//
#include <hip/hip_runtime.h>
#include <math.h>

#define BB 2
#define SDOC 2048
#define SSUM 1024
#define HD 768
#define NHEAD 12
#define DHEAD 64
#define FFD 3072
#define NLAYER 6
#define PD 256
#define NSPAN 32
#define WINSZ 256
#define QKVN 2304  // fused QKV output width

typedef short s16x8 __attribute__((ext_vector_type(8)));
typedef float f32x4 __attribute__((ext_vector_type(4)));

#define LDS_PTR(p) ((__attribute__((address_space(3))) void*)(p))
#define GLB_PTR(p) ((const __attribute__((address_space(1))) void*)(p))

// ---------------- bf16 helpers (RNE) ----------------
__device__ __forceinline__ unsigned short f2bf(float f) {
  unsigned int u = __builtin_bit_cast(unsigned int, f);
  unsigned int r = (u + 0x7fffu + ((u >> 16) & 1u)) >> 16;
  return (unsigned short)r;
}
__device__ __forceinline__ float bf2f(unsigned short h) {
  unsigned int u = ((unsigned int)h) << 16;
  return __builtin_bit_cast(float, u);
}

// ---------------- block reductions (blockDim == 256) ----------------
__device__ __forceinline__ float block_reduce_sum(float v) {
  __shared__ float sbuf[256];
  sbuf[threadIdx.x] = v;
  __syncthreads();
  for (int i = 128; i > 0; i >>= 1) {
    if ((int)threadIdx.x < i) sbuf[threadIdx.x] += sbuf[threadIdx.x + i];
    __syncthreads();
  }
  float r = sbuf[0];
  __syncthreads();
  return r;
}

__device__ __forceinline__ float block_reduce_max(float v) {
  __shared__ float mbuf[256];
  mbuf[threadIdx.x] = v;
  __syncthreads();
  for (int i = 128; i > 0; i >>= 1) {
    if ((int)threadIdx.x < i) mbuf[threadIdx.x] = fmaxf(mbuf[threadIdx.x], mbuf[threadIdx.x + i]);
    __syncthreads();
  }
  float r = mbuf[0];
  __syncthreads();
  return r;
}

// ---------------- embedding + LayerNorm + bf16 split pair ----------------
__global__ __launch_bounds__(256) void embed_ln_kernel(
    const int* __restrict__ ids, const float* __restrict__ we, const float* __restrict__ pe,
    const float* __restrict__ g, const float* __restrict__ bt, float* __restrict__ xout,
    unsigned short* __restrict__ xh, unsigned short* __restrict__ xl, int S) {
  int row = blockIdx.x;
  int s = row % S;
  int id = ids[row];
  int tid = threadIdx.x;
  float vals[3];
  float sum = 0.f;
#pragma unroll
  for (int i = 0; i < 3; i++) {
    int h = tid + i * 256;
    float t = we[(size_t)id * HD + h] + pe[(size_t)s * HD + h];
    vals[i] = t;
    sum += t;
  }
  float mean = block_reduce_sum(sum) * (1.f / HD);
  float vs = 0.f;
#pragma unroll
  for (int i = 0; i < 3; i++) { float d = vals[i] - mean; vs += d * d; }
  float var = block_reduce_sum(vs) * (1.f / HD);
  float inv = rsqrtf(var + 1e-5f);
#pragma unroll
  for (int i = 0; i < 3; i++) {
    int h = tid + i * 256;
    float v = (vals[i] - mean) * inv * g[h] + bt[h];
    size_t off = (size_t)row * HD + h;
    xout[off] = v;
    unsigned short hi = f2bf(v);
    xh[off] = hi;
    xl[off] = f2bf(v - bf2f(hi));
  }
}

// ---------------- LayerNorm (+optional residual, +optional bf16 pair) ----------------
__global__ __launch_bounds__(256) void ln_kernel(
    const float* __restrict__ a, const float* __restrict__ res,
    const float* __restrict__ g, const float* __restrict__ bt, float* __restrict__ out,
    unsigned short* __restrict__ oh, unsigned short* __restrict__ ol) {
  int row = blockIdx.x;
  int tid = threadIdx.x;
  const float* ar = a + (size_t)row * HD;
  const float* rr = res ? res + (size_t)row * HD : nullptr;
  float vals[3];
  float sum = 0.f;
#pragma unroll
  for (int i = 0; i < 3; i++) {
    int h = tid + i * 256;
    float t = ar[h] + (rr ? rr[h] : 0.f);
    vals[i] = t;
    sum += t;
  }
  float mean = block_reduce_sum(sum) * (1.f / HD);
  float vs = 0.f;
#pragma unroll
  for (int i = 0; i < 3; i++) { float d = vals[i] - mean; vs += d * d; }
  float var = block_reduce_sum(vs) * (1.f / HD);
  float inv = rsqrtf(var + 1e-5f);
#pragma unroll
  for (int i = 0; i < 3; i++) {
    int h = tid + i * 256;
    float v = (vals[i] - mean) * inv * g[h] + bt[h];
    size_t off = (size_t)row * HD + h;
    out[off] = v;
    if (oh) {
      unsigned short hi = f2bf(v);
      oh[off] = hi;
      ol[off] = f2bf(v - bf2f(hi));
    }
  }
}

// ---------------- per-layer weight transpose + split-cast ----------------
// outputs Bt (N,K) row-major, segments: QKV fused (N=2304,K=768) | WoT | Wf1T | Wf2T
__global__ __launch_bounds__(256) void tc_cast_kernel(
    const float* __restrict__ Wq, const float* __restrict__ Wk, const float* __restrict__ Wv,
    const float* __restrict__ Wo, const float* __restrict__ Wf1, const float* __restrict__ Wf2,
    unsigned short* __restrict__ oh, unsigned short* __restrict__ ol) {
  __shared__ float tile[32][33];
  int z = blockIdx.z;
  const float* W;
  int Kd, Nd;
  size_t off;
  switch (z) {
    case 0: W = Wq;  Kd = HD;  Nd = HD;  off = 0;        break;
    case 1: W = Wk;  Kd = HD;  Nd = HD;  off = 589824;   break;
    case 2: W = Wv;  Kd = HD;  Nd = HD;  off = 1179648;  break;
    case 3: W = Wo;  Kd = HD;  Nd = HD;  off = 1769472;  break;
    case 4: W = Wf1; Kd = HD;  Nd = FFD; off = 2359296;  break;
    default: W = Wf2; Kd = FFD; Nd = HD; off = 4718592;  break;
  }
  int tiles_n = Nd >> 5, tiles_k = Kd >> 5;
  int t = blockIdx.x;
  if (t >= tiles_n * tiles_k) return;
  int tn = t % tiles_n, tk = t / tiles_n;
  int n0 = tn * 32, k0 = tk * 32;
  int tid = threadIdx.x;
  int c = tid & 31, r0 = tid >> 5;
#pragma unroll
  for (int j = 0; j < 4; j++) {
    int r = r0 + j * 8;
    tile[r][c] = W[(size_t)(k0 + r) * Nd + n0 + c];
  }
  __syncthreads();
#pragma unroll
  for (int j = 0; j < 4; j++) {
    int r = r0 + j * 8;  // r = local n, c = local k
    float v = tile[c][r];
    size_t oidx = off + (size_t)(n0 + r) * Kd + k0 + c;
    unsigned short hi = f2bf(v);
    oh[oidx] = hi;
    ol[oidx] = f2bf(v - bf2f(hi));
  }
}

// ---------------- split-bf16 MFMA GEMM ----------------
// C(M,N) = (Ah+Al)(M,K) @ (Bh+Bl)^T  where B buffers are (N,K) row-major.
// bias: col c uses bias[c/seg][c%seg] with pointers b0,b1,b2.
// act=1: exact GELU. Output: fp32 C (if C) and/or bf16 pair Oh/Ol.
#define BM 128
#define BN 128
#define BKK 32
__global__ __launch_bounds__(256) void gemm_mfma_split(
    const unsigned short* __restrict__ Ah, const unsigned short* __restrict__ Al,
    const unsigned short* __restrict__ Bh, const unsigned short* __restrict__ Bl,
    const float* __restrict__ b0, const float* __restrict__ b1, const float* __restrict__ b2,
    int seg, float* __restrict__ C, unsigned short* __restrict__ Oh,
    unsigned short* __restrict__ Ol, int M, int N, int K, int act) {
  __shared__ __align__(16) unsigned short sAh[BM * BKK];
  __shared__ __align__(16) unsigned short sAl[BM * BKK];
  __shared__ __align__(16) unsigned short sBh[BN * BKK];
  __shared__ __align__(16) unsigned short sBl[BN * BKK];
  int tid = threadIdx.x;
  int bm = blockIdx.y * BM, bn = blockIdx.x * BN;
  int wave = tid >> 6, lane = tid & 63;
  int quad = lane >> 4, l16 = lane & 15;
  int wm = (wave >> 1) * 64, wn = (wave & 1) * 64;

  f32x4 zero = {0.f, 0.f, 0.f, 0.f};
  f32x4 acc[4][4];
#pragma unroll
  for (int i = 0; i < 4; i++)
#pragma unroll
    for (int j = 0; j < 4; j++) acc[i][j] = zero;

  int e0 = tid * 8;
  int row0 = e0 >> 5;  // /BKK
  int kk0 = e0 & (BKK - 1);

  for (int k0 = 0; k0 < K; k0 += BKK) {
    __syncthreads();
#pragma unroll
    for (int r = 0; r < 2; r++) {
      int row = row0 + r * 64;
      int le = (r * 256 + tid) * 8;
      size_t ga = (size_t)(bm + row) * K + k0 + kk0;
      size_t gb = (size_t)(bn + row) * K + k0 + kk0;
      __builtin_amdgcn_global_load_lds(GLB_PTR(Ah + ga), LDS_PTR(&sAh[le]), 16, 0, 0);
      __builtin_amdgcn_global_load_lds(GLB_PTR(Al + ga), LDS_PTR(&sAl[le]), 16, 0, 0);
      __builtin_amdgcn_global_load_lds(GLB_PTR(Bh + gb), LDS_PTR(&sBh[le]), 16, 0, 0);
      __builtin_amdgcn_global_load_lds(GLB_PTR(Bl + gb), LDS_PTR(&sBl[le]), 16, 0, 0);
    }
    __syncthreads();
    s16x8 afh[4], afl[4], bfh[4], bfl[4];
#pragma unroll
    for (int i = 0; i < 4; i++) {
      int arow = wm + i * 16 + l16;
      int brow = wn + i * 16 + l16;
      afh[i] = *(const s16x8*)&sAh[arow * BKK + quad * 8];
      afl[i] = *(const s16x8*)&sAl[arow * BKK + quad * 8];
      bfh[i] = *(const s16x8*)&sBh[brow * BKK + quad * 8];
      bfl[i] = *(const s16x8*)&sBl[brow * BKK + quad * 8];
    }
#pragma unroll
    for (int i = 0; i < 4; i++)
#pragma unroll
      for (int j = 0; j < 4; j++) {
        acc[i][j] = __builtin_amdgcn_mfma_f32_16x16x32_bf16(afh[i], bfh[j], acc[i][j], 0, 0, 0);
        acc[i][j] = __builtin_amdgcn_mfma_f32_16x16x32_bf16(afh[i], bfl[j], acc[i][j], 0, 0, 0);
        acc[i][j] = __builtin_amdgcn_mfma_f32_16x16x32_bf16(afl[i], bfh[j], acc[i][j], 0, 0, 0);
      }
  }

#pragma unroll
  for (int j = 0; j < 4; j++) {
    int col = bn + wn + j * 16 + l16;
    int bidx = col / seg;
    int boff = col - bidx * seg;
    const float* bp = bidx == 0 ? b0 : (bidx == 1 ? b1 : b2);
    float bv = bp[boff];
#pragma unroll
    for (int i = 0; i < 4; i++) {
#pragma unroll
      for (int r = 0; r < 4; r++) {
        int rowg = bm + wm + i * 16 + quad * 4 + r;
        float v = acc[i][j][r] + bv;
        if (act == 1) v = 0.5f * v * (1.f + erff(v * 0.70710678118654752f));
        size_t off = (size_t)rowg * N + col;
        if (C) C[off] = v;
        if (Oh) {
          unsigned short hi = f2bf(v);
          Oh[off] = hi;
          Ol[off] = f2bf(v - bf2f(hi));
        }
      }
    }
  }
}

// ---------------- fp32 tiled GEMM (tiny projections only) ----------------
#define GTM 64
#define GTN 64
#define GTK 16
__global__ __launch_bounds__(256) void gemm_f32(
    const float* __restrict__ A, const float* __restrict__ W, const float* __restrict__ bias,
    float* __restrict__ C, int M, int N, int K, int act) {
  __shared__ float As[GTK][GTM + 1];
  __shared__ float Bs[GTK][GTN + 1];
  int bm = blockIdx.y * GTM;
  int bn = blockIdx.x * GTN;
  int tid = threadIdx.x;
  int tx = tid & 15, ty = tid >> 4;
  float acc[4][4] = {{0.f}};
  for (int k0 = 0; k0 < K; k0 += GTK) {
    for (int e = tid; e < GTM * GTK; e += 256) {
      int m = e >> 4, kk = e & 15;
      int gm = bm + m;
      As[kk][m] = (gm < M) ? A[(size_t)gm * K + k0 + kk] : 0.f;
    }
    for (int e = tid; e < GTK * GTN; e += 256) {
      int kk = e >> 6, n = e & 63;
      Bs[kk][n] = W[(size_t)(k0 + kk) * N + bn + n];
    }
    __syncthreads();
#pragma unroll
    for (int kk = 0; kk < GTK; kk++) {
      float av[4], bv[4];
#pragma unroll
      for (int i = 0; i < 4; i++) av[i] = As[kk][ty * 4 + i];
#pragma unroll
      for (int j = 0; j < 4; j++) bv[j] = Bs[kk][tx * 4 + j];
#pragma unroll
      for (int i = 0; i < 4; i++)
#pragma unroll
        for (int j = 0; j < 4; j++) acc[i][j] += av[i] * bv[j];
    }
    __syncthreads();
  }
#pragma unroll
  for (int i = 0; i < 4; i++) {
    int gm = bm + ty * 4 + i;
    if (gm >= M) continue;
#pragma unroll
    for (int j = 0; j < 4; j++) {
      int gn = bn + tx * 4 + j;
      float v = acc[i][j] + bias[gn];
      if (act == 1) v = 0.5f * v * (1.f + erff(v * 0.70710678118654752f));
      C[(size_t)gm * N + gn] = v;
    }
  }
}

// ---------------- sliding-window attention (reads fused QKV, writes bf16 pair) ---------
#define QT 16
#define KSLOTS 576
__global__ __launch_bounds__(256) void attn_kernel(
    const float* __restrict__ qkv, const int* __restrict__ amask,
    unsigned short* __restrict__ Oh, unsigned short* __restrict__ Ol, int S) {
  __shared__ float sc[QT][KSLOTS];
  __shared__ float Qs[QT][DHEAD];
  __shared__ float Ks[64][DHEAD + 1];
  int b = blockIdx.z, hd = blockIdx.y;
  int p0 = blockIdx.x * QT;
  int tid = threadIdx.x;
  int kstart = p0 - WINSZ;
  const float* base = qkv + (size_t)(b * S) * QKVN + hd * DHEAD;

  for (int e = tid; e < QT * DHEAD; e += 256) {
    int q = e >> 6, d = e & 63;
    Qs[q][d] = base[(size_t)(p0 + q) * QKVN + d] * 0.125f;
  }
  for (int t = 0; t < 9; t++) {
    __syncthreads();
    for (int e = tid; e < 64 * DHEAD; e += 256) {
      int k = e >> 6, d = e & 63;
      int kp = kstart + t * 64 + k;
      Ks[k][d] = (kp >= 0 && kp < S) ? base[(size_t)kp * QKVN + HD + d] : 0.f;
    }
    __syncthreads();
    for (int e = tid; e < QT * 64; e += 256) {
      int q = e >> 6, k = e & 63;
      float acc = 0.f;
#pragma unroll
      for (int d = 0; d < DHEAD; d++) acc += Qs[q][d] * Ks[k][d];
      sc[q][t * 64 + k] = acc;
    }
  }
  __syncthreads();
  {
    int q = tid >> 4, l16 = tid & 15;
    float mx = -1e30f;
    for (int j = l16; j < KSLOTS; j += 16) {
      int kp = kstart + j;
      bool valid = (kp >= 0) && (kp < S) && (j >= q) && (j <= q + 2 * WINSZ) &&
                   (amask[b * S + kp] != 0);
      float v = valid ? sc[q][j] : -1e9f;
      sc[q][j] = v;
      mx = fmaxf(mx, v);
    }
    for (int off = 8; off > 0; off >>= 1) mx = fmaxf(mx, __shfl_down(mx, off, 16));
    mx = __shfl(mx, 0, 16);
    float sum = 0.f;
    for (int j = l16; j < KSLOTS; j += 16) {
      float e = expf(sc[q][j] - mx);
      sc[q][j] = e;
      sum += e;
    }
    for (int off = 8; off > 0; off >>= 1) sum += __shfl_down(sum, off, 16);
    sum = __shfl(sum, 0, 16);
    float inv = 1.f / sum;
    for (int j = l16; j < KSLOTS; j += 16) sc[q][j] *= inv;
  }
  float outv[4] = {0.f, 0.f, 0.f, 0.f};
  for (int t = 0; t < 9; t++) {
    __syncthreads();
    for (int e = tid; e < 64 * DHEAD; e += 256) {
      int k = e >> 6, d = e & 63;
      int kp = kstart + t * 64 + k;
      Ks[k][d] = (kp >= 0 && kp < S) ? base[(size_t)kp * QKVN + 2 * HD + d] : 0.f;
    }
    __syncthreads();
#pragma unroll
    for (int i = 0; i < 4; i++) {
      int e = tid + i * 256;
      int q = e >> 6, d = e & 63;
      float a = 0.f;
#pragma unroll
      for (int k = 0; k < 64; k++) a += sc[q][t * 64 + k] * Ks[k][d];
      outv[i] += a;
    }
  }
#pragma unroll
  for (int i = 0; i < 4; i++) {
    int e = tid + i * 256;
    int q = e >> 6, d = e & 63;
    size_t off = ((size_t)(b * S + p0 + q)) * HD + hd * DHEAD + d;
    unsigned short hi = f2bf(outv[i]);
    Oh[off] = hi;
    Ol[off] = f2bf(outv[i] - bf2f(hi));
  }
}

// ---------------- span pooling ----------------
__global__ __launch_bounds__(256) void pool_kernel(
    const float* __restrict__ seq, const int* __restrict__ spans, const int* __restrict__ sidx,
    const float* __restrict__ pw, float* __restrict__ emb, int S) {
  __shared__ float sc[2048];
  int ns = blockIdx.x;
  int bi = sidx[ns];
  const float* xb = seq + (size_t)bi * S * HD;
  int tid = threadIdx.x;
  for (int s = tid; s < S; s += 256) {
    float d = 0.f;
    const float* row = xb + (size_t)s * HD;
    for (int h = 0; h < HD; h++) d += row[h] * pw[h];
    d = fminf(fmaxf(d, -100.f), 100.f);
    sc[s] = (spans[ns * S + s] == 1) ? d : -1e9f;
  }
  __syncthreads();
  float mx = -1e30f;
  for (int s = tid; s < S; s += 256) mx = fmaxf(mx, sc[s]);
  mx = block_reduce_max(mx);
  float sum = 0.f;
  for (int s = tid; s < S; s += 256) {
    float e = expf(sc[s] - mx);
    sc[s] = e;
    sum += e;
  }
  sum = block_reduce_sum(sum);
  float inv = 1.f / sum;
  for (int h = tid; h < HD; h += 256) {
    float acc = 0.f;
    for (int s = 0; s < S; s++) acc += sc[s] * xb[(size_t)s * HD + h];
    emb[ns * HD + h] = acc * inv;
  }
}

// ---------------- final L2 normalize ----------------
__global__ __launch_bounds__(256) void norm_out_kernel(
    const float* __restrict__ proj, float* __restrict__ out) {
  int ns = blockIdx.x;
  float v = proj[ns * PD + threadIdx.x];
  float ss = block_reduce_sum(v * v);
  float n = fmaxf(sqrtf(ss), 1e-12f);
  out[ns * PD + threadIdx.x] = v / n;
}

// ---------------- host side ----------------
static void launch_gemm_f32(const float* A, const float* W, const float* bias, float* C,
                            int M, int N, int K, int act, hipStream_t stream) {
  dim3 grid((N + GTN - 1) / GTN, (M + GTM - 1) / GTM);
  gemm_f32<<<grid, 256, 0, stream>>>(A, W, bias, C, M, N, K, act);
}

static void launch_gemm_mfma(const unsigned short* Ah, const unsigned short* Al,
                             const unsigned short* Bh, const unsigned short* Bl,
                             const float* b0, const float* b1, const float* b2, int seg,
                             float* C, unsigned short* Oh, unsigned short* Ol,
                             int M, int N, int K, int act, hipStream_t stream) {
  dim3 grid(N / BN, M / BM);
  gemm_mfma_split<<<grid, 256, 0, stream>>>(Ah, Al, Bh, Bl, b0, b1, b2, seg, C, Oh, Ol,
                                            M, N, K, act);
}

// weight segment offsets in the per-layer transposed cache
#define WOFF_QKV 0
#define WOFF_O   1769472
#define WOFF_F1  2359296
#define WOFF_F2  4718592
#define WT_ELEMS 7077888

extern "C" void kernel_launch(void* const* d_in, const int* in_sizes, int n_in,
                              void* d_out, int out_size, void* d_ws, size_t ws_size,
                              hipStream_t stream) {
  const int* doc_ids   = (const int*)d_in[0];
  const int* doc_am    = (const int*)d_in[1];
  const int* sum_ids   = (const int*)d_in[2];
  const int* sum_am    = (const int*)d_in[3];
  const int* og_spans  = (const int*)d_in[4];
  const int* llm_spans = (const int*)d_in[5];
  const int* sidx      = (const int*)d_in[6];
  const float* word_emb = (const float*)d_in[7];
  const float* pos_emb  = (const float*)d_in[8];
  const float* emb_g = (const float*)d_in[9];
  const float* emb_b = (const float*)d_in[10];
  const float* Wq = (const float*)d_in[11];
  const float* bq = (const float*)d_in[12];
  const float* Wk = (const float*)d_in[13];
  const float* bk = (const float*)d_in[14];
  const float* Wv = (const float*)d_in[15];
  const float* bv = (const float*)d_in[16];
  const float* Wo = (const float*)d_in[17];
  const float* bo = (const float*)d_in[18];
  const float* lnag = (const float*)d_in[19];
  const float* lnab = (const float*)d_in[20];
  const float* Wf1 = (const float*)d_in[21];
  const float* bf1 = (const float*)d_in[22];
  const float* Wf2 = (const float*)d_in[23];
  const float* bf2 = (const float*)d_in[24];
  const float* lnfg = (const float*)d_in[25];
  const float* lnfb = (const float*)d_in[26];
  const float* pool_w = (const float*)d_in[27];
  const float* pj_g1 = (const float*)d_in[28];
  const float* pj_b1 = (const float*)d_in[29];
  const float* pj_W1 = (const float*)d_in[30];
  const float* pj_c1 = (const float*)d_in[31];
  const float* pj_g2 = (const float*)d_in[32];
  const float* pj_b2 = (const float*)d_in[33];
  const float* pj_W2 = (const float*)d_in[34];
  const float* pj_c2 = (const float*)d_in[35];
  float* out = (float*)d_out;

  // ---- workspace layout ----
  const size_t n_xd  = (size_t)BB * SDOC * HD;   // 3,145,728
  const size_t n_xs  = (size_t)BB * SSUM * HD;   // 1,572,864
  const size_t n_qkv = (size_t)BB * SDOC * QKVN; // 9,437,184
  const size_t n_h   = (size_t)BB * SDOC * FFD;  // 12,582,912

  float* xd   = (float*)d_ws;
  float* xs   = xd + n_xd;
  float* qkvb = xs + n_xs;           // fused QKV out / O-proj out / FFN2 out
  float* emb  = qkvb + n_qkv;
  float* h2   = emb + NSPAN * HD;
  float* proj = h2 + NSPAN * HD;
  unsigned short* x_hi = (unsigned short*)(proj + NSPAN * PD);
  unsigned short* x_lo  = x_hi + n_xd;
  unsigned short* ab_hi = x_lo + n_xd;
  unsigned short* ab_lo = ab_hi + n_xd;
  unsigned short* h_hi  = ab_lo + n_xd;
  unsigned short* h_lo  = h_hi + n_h;
  unsigned short* wt_hi = h_lo + n_h;
  unsigned short* wt_lo = wt_hi + WT_ELEMS;

  for (int pass = 0; pass < 2; pass++) {
    int S = (pass == 0) ? SDOC : SSUM;
    const int* ids = (pass == 0) ? doc_ids : sum_ids;
    const int* am  = (pass == 0) ? doc_am : sum_am;
    float* x = (pass == 0) ? xd : xs;
    int M = BB * S;
    embed_ln_kernel<<<M, 256, 0, stream>>>(ids, word_emb, pos_emb, emb_g, emb_b,
                                           x, x_hi, x_lo, S);
    for (int l = 0; l < NLAYER; l++) {
      tc_cast_kernel<<<dim3(2304, 1, 6), 256, 0, stream>>>(
          Wq + (size_t)l * HD * HD, Wk + (size_t)l * HD * HD, Wv + (size_t)l * HD * HD,
          Wo + (size_t)l * HD * HD, Wf1 + (size_t)l * HD * FFD, Wf2 + (size_t)l * FFD * HD,
          wt_hi, wt_lo);
      // fused QKV: (M,2304) = x @ [Wq|Wk|Wv]
      launch_gemm_mfma(x_hi, x_lo, wt_hi + WOFF_QKV, wt_lo + WOFF_QKV,
                       bq + l * HD, bk + l * HD, bv + l * HD, HD,
                       qkvb, nullptr, nullptr, M, QKVN, HD, 0, stream);
      attn_kernel<<<dim3(S / QT, NHEAD, BB), 256, 0, stream>>>(qkvb, am, ab_hi, ab_lo, S);
      // O-proj -> qkvb (fp32)
      launch_gemm_mfma(ab_hi, ab_lo, wt_hi + WOFF_O, wt_lo + WOFF_O,
                       bo + l * HD, bo + l * HD, bo + l * HD, HD,
                       qkvb, nullptr, nullptr, M, HD, HD, 0, stream);
      ln_kernel<<<M, 256, 0, stream>>>(qkvb, x, lnag + l * HD, lnab + l * HD, x, x_hi, x_lo);
      // FFN1 + GELU -> bf16 pair only
      launch_gemm_mfma(x_hi, x_lo, wt_hi + WOFF_F1, wt_lo + WOFF_F1,
                       bf1 + l * FFD, bf1 + l * FFD, bf1 + l * FFD, FFD,
                       nullptr, h_hi, h_lo, M, FFD, HD, 1, stream);
      // FFN2 -> qkvb (fp32)
      launch_gemm_mfma(h_hi, h_lo, wt_hi + WOFF_F2, wt_lo + WOFF_F2,
                       bf2 + l * HD, bf2 + l * HD, bf2 + l * HD, HD,
                       qkvb, nullptr, nullptr, M, HD, FFD, 0, stream);
      ln_kernel<<<M, 256, 0, stream>>>(qkvb, x, lnfg + l * HD, lnfb + l * HD, x, x_hi, x_lo);
    }
  }

  for (int pass = 0; pass < 2; pass++) {
    const float* seq = (pass == 0) ? xd : xs;
    const int* spans = (pass == 0) ? og_spans : llm_spans;
    int S = (pass == 0) ? SDOC : SSUM;
    pool_kernel<<<NSPAN, 256, 0, stream>>>(seq, spans, sidx, pool_w, emb, S);
    ln_kernel<<<NSPAN, 256, 0, stream>>>(emb, nullptr, pj_g1, pj_b1, h2, nullptr, nullptr);
    launch_gemm_f32(h2, pj_W1, pj_c1, emb, NSPAN, HD, HD, 1, stream);
    ln_kernel<<<NSPAN, 256, 0, stream>>>(emb, nullptr, pj_g2, pj_b2, h2, nullptr, nullptr);
    launch_gemm_f32(h2, pj_W2, pj_c2, proj, NSPAN, PD, HD, 0, stream);
    norm_out_kernel<<<NSPAN, 256, 0, stream>>>(proj, out + pass * NSPAN * PD);
  }
}

// Round 3
// 3836.050 us; speedup vs baseline: 7.1123x; 2.9957x over previous
//
#include <hip/hip_runtime.h>
#include <math.h>

#define BB 2
#define SDOC 2048
#define SSUM 1024
#define HD 768
#define NHEAD 12
#define DHEAD 64
#define FFD 3072
#define NLAYER 6
#define PD 256
#define NSPAN 32
#define WINSZ 256
#define QKVN 2304  // fused QKV output width

typedef short s16x8 __attribute__((ext_vector_type(8)));
typedef float f32x4 __attribute__((ext_vector_type(4)));

#define LDS_PTR(p) ((__attribute__((address_space(3))) void*)(p))
#define GLB_PTR(p) ((const __attribute__((address_space(1))) void*)(p))

// ---------------- bf16 helpers (RNE) ----------------
__device__ __forceinline__ unsigned short f2bf(float f) {
  unsigned int u = __builtin_bit_cast(unsigned int, f);
  unsigned int r = (u + 0x7fffu + ((u >> 16) & 1u)) >> 16;
  return (unsigned short)r;
}
__device__ __forceinline__ float bf2f(unsigned short h) {
  unsigned int u = ((unsigned int)h) << 16;
  return __builtin_bit_cast(float, u);
}

// ---------------- block reductions (blockDim == 256) ----------------
__device__ __forceinline__ float block_reduce_sum(float v) {
  __shared__ float sbuf[256];
  sbuf[threadIdx.x] = v;
  __syncthreads();
  for (int i = 128; i > 0; i >>= 1) {
    if ((int)threadIdx.x < i) sbuf[threadIdx.x] += sbuf[threadIdx.x + i];
    __syncthreads();
  }
  float r = sbuf[0];
  __syncthreads();
  return r;
}

__device__ __forceinline__ float block_reduce_max(float v) {
  __shared__ float mbuf[256];
  mbuf[threadIdx.x] = v;
  __syncthreads();
  for (int i = 128; i > 0; i >>= 1) {
    if ((int)threadIdx.x < i) mbuf[threadIdx.x] = fmaxf(mbuf[threadIdx.x], mbuf[threadIdx.x + i]);
    __syncthreads();
  }
  float r = mbuf[0];
  __syncthreads();
  return r;
}

// ---------------- embedding + LayerNorm + bf16 ----------------
__global__ __launch_bounds__(256) void embed_ln_kernel(
    const int* __restrict__ ids, const float* __restrict__ we, const float* __restrict__ pe,
    const float* __restrict__ g, const float* __restrict__ bt, float* __restrict__ xout,
    unsigned short* __restrict__ xb, int S) {
  int row = blockIdx.x;
  int s = row % S;
  int id = ids[row];
  int tid = threadIdx.x;
  float vals[3];
  float sum = 0.f;
#pragma unroll
  for (int i = 0; i < 3; i++) {
    int h = tid + i * 256;
    float t = we[(size_t)id * HD + h] + pe[(size_t)s * HD + h];
    vals[i] = t;
    sum += t;
  }
  float mean = block_reduce_sum(sum) * (1.f / HD);
  float vs = 0.f;
#pragma unroll
  for (int i = 0; i < 3; i++) { float d = vals[i] - mean; vs += d * d; }
  float var = block_reduce_sum(vs) * (1.f / HD);
  float inv = rsqrtf(var + 1e-5f);
#pragma unroll
  for (int i = 0; i < 3; i++) {
    int h = tid + i * 256;
    float v = (vals[i] - mean) * inv * g[h] + bt[h];
    size_t off = (size_t)row * HD + h;
    xout[off] = v;
    xb[off] = f2bf(v);
  }
}

// ---------------- LayerNorm (+optional residual, +optional bf16 out) ----------------
__global__ __launch_bounds__(256) void ln_kernel(
    const float* __restrict__ a, const float* __restrict__ res,
    const float* __restrict__ g, const float* __restrict__ bt, float* __restrict__ out,
    unsigned short* __restrict__ ob) {
  int row = blockIdx.x;
  int tid = threadIdx.x;
  const float* ar = a + (size_t)row * HD;
  const float* rr = res ? res + (size_t)row * HD : nullptr;
  float vals[3];
  float sum = 0.f;
#pragma unroll
  for (int i = 0; i < 3; i++) {
    int h = tid + i * 256;
    float t = ar[h] + (rr ? rr[h] : 0.f);
    vals[i] = t;
    sum += t;
  }
  float mean = block_reduce_sum(sum) * (1.f / HD);
  float vs = 0.f;
#pragma unroll
  for (int i = 0; i < 3; i++) { float d = vals[i] - mean; vs += d * d; }
  float var = block_reduce_sum(vs) * (1.f / HD);
  float inv = rsqrtf(var + 1e-5f);
#pragma unroll
  for (int i = 0; i < 3; i++) {
    int h = tid + i * 256;
    float v = (vals[i] - mean) * inv * g[h] + bt[h];
    size_t off = (size_t)row * HD + h;
    out[off] = v;
    if (ob) ob[off] = f2bf(v);
  }
}

// ---------------- per-layer weight transpose + bf16 cast ----------------
// outputs Bt (N,K) row-major bf16: QKV fused | WoT | Wf1T | Wf2T
__global__ __launch_bounds__(256) void tc_cast_kernel(
    const float* __restrict__ Wq, const float* __restrict__ Wk, const float* __restrict__ Wv,
    const float* __restrict__ Wo, const float* __restrict__ Wf1, const float* __restrict__ Wf2,
    unsigned short* __restrict__ ob) {
  __shared__ float tile[32][33];
  int z = blockIdx.z;
  const float* W;
  int Kd, Nd;
  size_t off;
  switch (z) {
    case 0: W = Wq;  Kd = HD;  Nd = HD;  off = 0;        break;
    case 1: W = Wk;  Kd = HD;  Nd = HD;  off = 589824;   break;
    case 2: W = Wv;  Kd = HD;  Nd = HD;  off = 1179648;  break;
    case 3: W = Wo;  Kd = HD;  Nd = HD;  off = 1769472;  break;
    case 4: W = Wf1; Kd = HD;  Nd = FFD; off = 2359296;  break;
    default: W = Wf2; Kd = FFD; Nd = HD; off = 4718592;  break;
  }
  int tiles_n = Nd >> 5, tiles_k = Kd >> 5;
  int t = blockIdx.x;
  if (t >= tiles_n * tiles_k) return;
  int tn = t % tiles_n, tk = t / tiles_n;
  int n0 = tn * 32, k0 = tk * 32;
  int tid = threadIdx.x;
  int c = tid & 31, r0 = tid >> 5;
#pragma unroll
  for (int j = 0; j < 4; j++) {
    int r = r0 + j * 8;
    tile[r][c] = W[(size_t)(k0 + r) * Nd + n0 + c];
  }
  __syncthreads();
#pragma unroll
  for (int j = 0; j < 4; j++) {
    int r = r0 + j * 8;  // r = local n, c = local k
    ob[off + (size_t)(n0 + r) * Kd + k0 + c] = f2bf(tile[c][r]);
  }
}

// ---------------- bf16 MFMA GEMM ----------------
// C(M,N) = A(M,K)bf16 @ B^T, B stored (N,K) row-major bf16.
// bias segments: col c -> bias[c/seg] ptr b0/b1/b2, offset c%seg.
// act=1: exact GELU. Output fp32 C (if non-null) and/or bf16 Oh (if non-null).
#define BM 128
#define BN 128
#define BKK 32
__global__ __launch_bounds__(256) void gemm_mfma(
    const unsigned short* __restrict__ A, const unsigned short* __restrict__ B,
    const float* __restrict__ b0, const float* __restrict__ b1, const float* __restrict__ b2,
    int seg, float* __restrict__ C, unsigned short* __restrict__ Oh,
    int M, int N, int K, int act) {
  __shared__ __align__(16) unsigned short sA[BM * BKK];
  __shared__ __align__(16) unsigned short sB[BN * BKK];
  int tid = threadIdx.x;
  int bm = blockIdx.y * BM, bn = blockIdx.x * BN;
  int wave = tid >> 6, lane = tid & 63;
  int quad = lane >> 4, l16 = lane & 15;
  int wm = (wave >> 1) * 64, wn = (wave & 1) * 64;

  f32x4 zero = {0.f, 0.f, 0.f, 0.f};
  f32x4 acc[4][4];
#pragma unroll
  for (int i = 0; i < 4; i++)
#pragma unroll
    for (int j = 0; j < 4; j++) acc[i][j] = zero;

  int e0 = tid * 8;
  int row0 = e0 >> 5;
  int kk0 = e0 & (BKK - 1);

  for (int k0 = 0; k0 < K; k0 += BKK) {
    __syncthreads();
#pragma unroll
    for (int r = 0; r < 2; r++) {
      int row = row0 + r * 64;
      int le = (r * 256 + tid) * 8;
      size_t ga = (size_t)(bm + row) * K + k0 + kk0;
      size_t gb = (size_t)(bn + row) * K + k0 + kk0;
      __builtin_amdgcn_global_load_lds(GLB_PTR(A + ga), LDS_PTR(&sA[le]), 16, 0, 0);
      __builtin_amdgcn_global_load_lds(GLB_PTR(B + gb), LDS_PTR(&sB[le]), 16, 0, 0);
    }
    __syncthreads();
    s16x8 af[4], bf[4];
#pragma unroll
    for (int i = 0; i < 4; i++) {
      af[i] = *(const s16x8*)&sA[(wm + i * 16 + l16) * BKK + quad * 8];
      bf[i] = *(const s16x8*)&sB[(wn + i * 16 + l16) * BKK + quad * 8];
    }
#pragma unroll
    for (int i = 0; i < 4; i++)
#pragma unroll
      for (int j = 0; j < 4; j++)
        acc[i][j] = __builtin_amdgcn_mfma_f32_16x16x32_bf16(af[i], bf[j], acc[i][j], 0, 0, 0);
  }

#pragma unroll
  for (int j = 0; j < 4; j++) {
    int col = bn + wn + j * 16 + l16;
    int bidx = col / seg;
    int boff = col - bidx * seg;
    const float* bp = bidx == 0 ? b0 : (bidx == 1 ? b1 : b2);
    float bv = bp[boff];
#pragma unroll
    for (int i = 0; i < 4; i++) {
#pragma unroll
      for (int r = 0; r < 4; r++) {
        int rowg = bm + wm + i * 16 + quad * 4 + r;
        float v = acc[i][j][r] + bv;
        if (act == 1) v = 0.5f * v * (1.f + erff(v * 0.70710678118654752f));
        size_t off = (size_t)rowg * N + col;
        if (C) C[off] = v;
        if (Oh) Oh[off] = f2bf(v);
      }
    }
  }
}

// ---------------- fp32 tiled GEMM (tiny projections only) ----------------
#define GTM 64
#define GTN 64
#define GTK 16
__global__ __launch_bounds__(256) void gemm_f32(
    const float* __restrict__ A, const float* __restrict__ W, const float* __restrict__ bias,
    float* __restrict__ C, int M, int N, int K, int act) {
  __shared__ float As[GTK][GTM + 1];
  __shared__ float Bs[GTK][GTN + 1];
  int bm = blockIdx.y * GTM;
  int bn = blockIdx.x * GTN;
  int tid = threadIdx.x;
  int tx = tid & 15, ty = tid >> 4;
  float acc[4][4] = {{0.f}};
  for (int k0 = 0; k0 < K; k0 += GTK) {
    for (int e = tid; e < GTM * GTK; e += 256) {
      int m = e >> 4, kk = e & 15;
      int gm = bm + m;
      As[kk][m] = (gm < M) ? A[(size_t)gm * K + k0 + kk] : 0.f;
    }
    for (int e = tid; e < GTK * GTN; e += 256) {
      int kk = e >> 6, n = e & 63;
      Bs[kk][n] = W[(size_t)(k0 + kk) * N + bn + n];
    }
    __syncthreads();
#pragma unroll
    for (int kk = 0; kk < GTK; kk++) {
      float av[4], bv[4];
#pragma unroll
      for (int i = 0; i < 4; i++) av[i] = As[kk][ty * 4 + i];
#pragma unroll
      for (int j = 0; j < 4; j++) bv[j] = Bs[kk][tx * 4 + j];
#pragma unroll
      for (int i = 0; i < 4; i++)
#pragma unroll
        for (int j = 0; j < 4; j++) acc[i][j] += av[i] * bv[j];
    }
    __syncthreads();
  }
#pragma unroll
  for (int i = 0; i < 4; i++) {
    int gm = bm + ty * 4 + i;
    if (gm >= M) continue;
#pragma unroll
    for (int j = 0; j < 4; j++) {
      int gn = bn + tx * 4 + j;
      float v = acc[i][j] + bias[gn];
      if (act == 1) v = 0.5f * v * (1.f + erff(v * 0.70710678118654752f));
      C[(size_t)gm * N + gn] = v;
    }
  }
}

// ---------------- MFMA sliding-window attention ----------------
// block = (64 queries, head, batch); 4 waves, wave w owns queries [w*16, w*16+16).
// Online softmax; keys [p0-256, p0+320) in 9 tiles of 64.
#define AQT 64
__global__ __launch_bounds__(256) void attn_mfma(
    const unsigned short* __restrict__ qkv, const int* __restrict__ amask,
    unsigned short* __restrict__ Oh, int S) {
  __shared__ unsigned short Vs[64][72];      // V^T: [d][key], +8 pad
  __shared__ unsigned short Ps[4][16][72];   // per-wave P (query, key), +8 pad
  int b = blockIdx.z, hd = blockIdx.y;
  int p0 = blockIdx.x * AQT;
  int tid = threadIdx.x;
  int wave = tid >> 6, lane = tid & 63;
  int quad = lane >> 4, l16 = lane & 15;
  int kstart = p0 - WINSZ;
  const unsigned short* base = qkv + (size_t)(b * S) * QKVN + hd * DHEAD;

  // Q fragments (A-layout): m = l16 (query in wave tile), k = d
  s16x8 aq[2];
  {
    const unsigned short* qrow = base + (size_t)(p0 + wave * 16 + l16) * QKVN;
    aq[0] = *(const s16x8*)(qrow + quad * 8);
    aq[1] = *(const s16x8*)(qrow + 32 + quad * 8);
  }
  f32x4 o[4];
  f32x4 zero = {0.f, 0.f, 0.f, 0.f};
#pragma unroll
  for (int i = 0; i < 4; i++) o[i] = zero;
  float mi[4] = {-1e30f, -1e30f, -1e30f, -1e30f};
  float li[4] = {0.f, 0.f, 0.f, 0.f};

  for (int t = 0; t < 9; t++) {
    __syncthreads();  // prior PV reads of Vs done
    {
      // stage V^T: thread handles key=tid&63, d in [ (tid>>6)*16, +16 )
      int key = tid & 63, d0 = (tid >> 6) * 16;
      int kp = kstart + t * 64 + key;
      if (kp >= 0 && kp < S) {
        const unsigned short* vrow = base + (size_t)kp * QKVN + 2 * HD + d0;
        s16x8 v0 = *(const s16x8*)(vrow);
        s16x8 v1 = *(const s16x8*)(vrow + 8);
#pragma unroll
        for (int j = 0; j < 8; j++) Vs[d0 + j][key] = (unsigned short)v0[j];
#pragma unroll
        for (int j = 0; j < 8; j++) Vs[d0 + 8 + j][key] = (unsigned short)v1[j];
      } else {
#pragma unroll
        for (int j = 0; j < 16; j++) Vs[d0 + j][key] = 0;
      }
    }
    __syncthreads();

    // QK^T: S-tile 16q x 64k per wave (4 n-tiles)
    f32x4 sc[4];
#pragma unroll
    for (int nt = 0; nt < 4; nt++) {
      int kr = kstart + t * 64 + nt * 16 + l16;
      s16x8 bk0 = {0, 0, 0, 0, 0, 0, 0, 0}, bk1 = bk0;
      if (kr >= 0 && kr < S) {
        const unsigned short* krow = base + (size_t)kr * QKVN + HD;
        bk0 = *(const s16x8*)(krow + quad * 8);
        bk1 = *(const s16x8*)(krow + 32 + quad * 8);
      }
      sc[nt] = __builtin_amdgcn_mfma_f32_16x16x32_bf16(aq[0], bk0, zero, 0, 0, 0);
      sc[nt] = __builtin_amdgcn_mfma_f32_16x16x32_bf16(aq[1], bk1, sc[nt], 0, 0, 0);
    }

    // mask + scale; tile row max
    float s_val[4][4];  // [nt][r]
    float tm[4] = {-1e30f, -1e30f, -1e30f, -1e30f};
#pragma unroll
    for (int nt = 0; nt < 4; nt++) {
      int j = t * 64 + nt * 16 + l16;
      int kp = kstart + j;
      int am = (kp >= 0 && kp < S) ? amask[b * S + kp] : 0;
#pragma unroll
      for (int r = 0; r < 4; r++) {
        int ql = wave * 16 + quad * 4 + r;
        bool valid = (am != 0) && (j >= ql) && (j <= ql + 512);
        float v = valid ? sc[nt][r] * 0.125f : -1e9f;
        s_val[nt][r] = v;
        tm[r] = fmaxf(tm[r], v);
      }
    }
#pragma unroll
    for (int m = 1; m < 16; m <<= 1)
#pragma unroll
      for (int r = 0; r < 4; r++) tm[r] = fmaxf(tm[r], __shfl_xor(tm[r], m, 16));

    float alpha[4], rs[4];
#pragma unroll
    for (int r = 0; r < 4; r++) {
      float mn = fmaxf(mi[r], tm[r]);
      alpha[r] = __expf(mi[r] - mn);
      mi[r] = mn;
      rs[r] = 0.f;
    }
#pragma unroll
    for (int nt = 0; nt < 4; nt++)
#pragma unroll
      for (int r = 0; r < 4; r++) {
        float p = __expf(s_val[nt][r] - mi[r]);
        rs[r] += p;
        Ps[wave][quad * 4 + r][nt * 16 + l16] = f2bf(p);
      }
#pragma unroll
    for (int m = 1; m < 16; m <<= 1)
#pragma unroll
      for (int r = 0; r < 4; r++) rs[r] += __shfl_xor(rs[r], m, 16);
#pragma unroll
    for (int r = 0; r < 4; r++) li[r] = li[r] * alpha[r] + rs[r];
#pragma unroll
    for (int dn = 0; dn < 4; dn++)
#pragma unroll
      for (int r = 0; r < 4; r++) o[dn][r] *= alpha[r];

    // PV: A = P (m=q, k=key), B = V^T (n=d, k=key)
#pragma unroll
    for (int ks = 0; ks < 2; ks++) {
      s16x8 ap = *(const s16x8*)&Ps[wave][l16][ks * 32 + quad * 8];
#pragma unroll
      for (int dn = 0; dn < 4; dn++) {
        s16x8 bv = *(const s16x8*)&Vs[dn * 16 + l16][ks * 32 + quad * 8];
        o[dn] = __builtin_amdgcn_mfma_f32_16x16x32_bf16(ap, bv, o[dn], 0, 0, 0);
      }
    }
  }

  // epilogue: O / l, write bf16
#pragma unroll
  for (int r = 0; r < 4; r++) {
    float inv = 1.f / li[r];
    int rowg = b * S + p0 + wave * 16 + quad * 4 + r;
#pragma unroll
    for (int dn = 0; dn < 4; dn++) {
      Oh[(size_t)rowg * HD + hd * DHEAD + dn * 16 + l16] = f2bf(o[dn][r] * inv);
    }
  }
}

// ---------------- pooling path ----------------
// dots[row] = clip(dot(x[row], pw), +-100); one wave per row
__global__ __launch_bounds__(256) void dots_kernel(
    const float* __restrict__ x, const float* __restrict__ pw, float* __restrict__ dots) {
  int row = blockIdx.x * 4 + (threadIdx.x >> 6);
  int lane = threadIdx.x & 63;
  const float* r = x + (size_t)row * HD;
  float s = 0.f;
  for (int i = lane; i < HD; i += 64) s += r[i] * pw[i];
#pragma unroll
  for (int m = 32; m > 0; m >>= 1) s += __shfl_xor(s, m, 64);
  if (lane == 0) dots[row] = fminf(fmaxf(s, -100.f), 100.f);
}

// masked softmax over S per span -> probs
__global__ __launch_bounds__(256) void span_softmax_kernel(
    const float* __restrict__ dots, const int* __restrict__ spans,
    const int* __restrict__ sidx, float* __restrict__ probs, int S) {
  int ns = blockIdx.x;
  int bi = sidx[ns];
  int tid = threadIdx.x;
  float mx = -1e30f;
  for (int s = tid; s < S; s += 256) {
    float v = (spans[ns * S + s] == 1) ? dots[bi * S + s] : -1e9f;
    mx = fmaxf(mx, v);
  }
  mx = block_reduce_max(mx);
  float sum = 0.f;
  for (int s = tid; s < S; s += 256) {
    float v = (spans[ns * S + s] == 1) ? dots[bi * S + s] : -1e9f;
    float e = __expf(v - mx);
    probs[ns * S + s] = e;
    sum += e;
  }
  sum = block_reduce_sum(sum);
  float inv = 1.f / sum;
  for (int s = tid; s < S; s += 256) probs[ns * S + s] *= inv;
}

// pooled[ns][h] += sum_{s in seg} probs[ns][s] * seq[bi][s][h]
__global__ __launch_bounds__(256) void wsum_kernel(
    const float* __restrict__ seq, const float* __restrict__ probs,
    const int* __restrict__ sidx, float* __restrict__ pooled, int S) {
  __shared__ float ps[256];
  int ns = blockIdx.y;
  int s0 = blockIdx.x * 256;
  int bi = sidx[ns];
  int tid = threadIdx.x;
  ps[tid] = probs[ns * S + s0 + tid];
  __syncthreads();
  const float* xb = seq + ((size_t)bi * S + s0) * HD;
  float a0 = 0.f, a1 = 0.f, a2 = 0.f;
  for (int s = 0; s < 256; s++) {
    float p = ps[s];
    const float* row = xb + (size_t)s * HD;
    a0 += p * row[tid];
    a1 += p * row[tid + 256];
    a2 += p * row[tid + 512];
  }
  atomicAdd(&pooled[ns * HD + tid], a0);
  atomicAdd(&pooled[ns * HD + tid + 256], a1);
  atomicAdd(&pooled[ns * HD + tid + 512], a2);
}

// ---------------- final L2 normalize ----------------
__global__ __launch_bounds__(256) void norm_out_kernel(
    const float* __restrict__ proj, float* __restrict__ out) {
  int ns = blockIdx.x;
  float v = proj[ns * PD + threadIdx.x];
  float ss = block_reduce_sum(v * v);
  float n = fmaxf(sqrtf(ss), 1e-12f);
  out[ns * PD + threadIdx.x] = v / n;
}

// ---------------- host side ----------------
static void launch_gemm_f32(const float* A, const float* W, const float* bias, float* C,
                            int M, int N, int K, int act, hipStream_t stream) {
  dim3 grid((N + GTN - 1) / GTN, (M + GTM - 1) / GTM);
  gemm_f32<<<grid, 256, 0, stream>>>(A, W, bias, C, M, N, K, act);
}

static void launch_gemm_mfma(const unsigned short* A, const unsigned short* B,
                             const float* b0, const float* b1, const float* b2, int seg,
                             float* C, unsigned short* Oh,
                             int M, int N, int K, int act, hipStream_t stream) {
  dim3 grid(N / BN, M / BM);
  gemm_mfma<<<grid, 256, 0, stream>>>(A, B, b0, b1, b2, seg, C, Oh, M, N, K, act);
}

// weight segment offsets in the per-layer transposed cache (elements)
#define WOFF_QKV 0
#define WOFF_O   1769472
#define WOFF_F1  2359296
#define WOFF_F2  4718592
#define WT_ELEMS 7077888

extern "C" void kernel_launch(void* const* d_in, const int* in_sizes, int n_in,
                              void* d_out, int out_size, void* d_ws, size_t ws_size,
                              hipStream_t stream) {
  const int* doc_ids   = (const int*)d_in[0];
  const int* doc_am    = (const int*)d_in[1];
  const int* sum_ids   = (const int*)d_in[2];
  const int* sum_am    = (const int*)d_in[3];
  const int* og_spans  = (const int*)d_in[4];
  const int* llm_spans = (const int*)d_in[5];
  const int* sidx      = (const int*)d_in[6];
  const float* word_emb = (const float*)d_in[7];
  const float* pos_emb  = (const float*)d_in[8];
  const float* emb_g = (const float*)d_in[9];
  const float* emb_b = (const float*)d_in[10];
  const float* Wq = (const float*)d_in[11];
  const float* bq = (const float*)d_in[12];
  const float* Wk = (const float*)d_in[13];
  const float* bk = (const float*)d_in[14];
  const float* Wv = (const float*)d_in[15];
  const float* bv = (const float*)d_in[16];
  const float* Wo = (const float*)d_in[17];
  const float* bo = (const float*)d_in[18];
  const float* lnag = (const float*)d_in[19];
  const float* lnab = (const float*)d_in[20];
  const float* Wf1 = (const float*)d_in[21];
  const float* bf1 = (const float*)d_in[22];
  const float* Wf2 = (const float*)d_in[23];
  const float* bf2 = (const float*)d_in[24];
  const float* lnfg = (const float*)d_in[25];
  const float* lnfb = (const float*)d_in[26];
  const float* pool_w = (const float*)d_in[27];
  const float* pj_g1 = (const float*)d_in[28];
  const float* pj_b1 = (const float*)d_in[29];
  const float* pj_W1 = (const float*)d_in[30];
  const float* pj_c1 = (const float*)d_in[31];
  const float* pj_g2 = (const float*)d_in[32];
  const float* pj_b2 = (const float*)d_in[33];
  const float* pj_W2 = (const float*)d_in[34];
  const float* pj_c2 = (const float*)d_in[35];
  float* out = (float*)d_out;

  // ---- workspace layout (~106 MB) ----
  const size_t n_xd = (size_t)BB * SDOC * HD;   // 3,145,728
  const size_t n_xs = (size_t)BB * SSUM * HD;   // 1,572,864
  float* xd     = (float*)d_ws;
  float* xs     = xd + n_xd;
  float* cbuf   = xs + n_xs;                    // fp32 GEMM out (O-proj / FFN2), M*768 max
  float* pooled = cbuf + n_xd;
  float* g1     = pooled + NSPAN * HD;
  float* h2     = g1 + NSPAN * HD;
  float* proj   = h2 + NSPAN * HD;
  float* dots   = proj + NSPAN * PD;
  float* probs  = dots + BB * SDOC;
  unsigned short* xbf_d  = (unsigned short*)(probs + NSPAN * SDOC);
  unsigned short* xbf_s  = xbf_d + n_xd;
  unsigned short* qkv_bf = xbf_s + n_xs;                       // BB*SDOC*2304
  unsigned short* ab_bf  = qkv_bf + (size_t)BB * SDOC * QKVN;  // BB*SDOC*768
  unsigned short* h_bf   = ab_bf + n_xd;                       // BB*SDOC*3072
  unsigned short* wt_bf  = h_bf + (size_t)BB * SDOC * FFD;     // one layer's weights

  embed_ln_kernel<<<BB * SDOC, 256, 0, stream>>>(doc_ids, word_emb, pos_emb, emb_g, emb_b,
                                                 xd, xbf_d, SDOC);
  embed_ln_kernel<<<BB * SSUM, 256, 0, stream>>>(sum_ids, word_emb, pos_emb, emb_g, emb_b,
                                                 xs, xbf_s, SSUM);

  for (int l = 0; l < NLAYER; l++) {
    tc_cast_kernel<<<dim3(2304, 1, 6), 256, 0, stream>>>(
        Wq + (size_t)l * HD * HD, Wk + (size_t)l * HD * HD, Wv + (size_t)l * HD * HD,
        Wo + (size_t)l * HD * HD, Wf1 + (size_t)l * HD * FFD, Wf2 + (size_t)l * FFD * HD,
        wt_bf);
    for (int pass = 0; pass < 2; pass++) {
      int S = (pass == 0) ? SDOC : SSUM;
      const int* am = (pass == 0) ? doc_am : sum_am;
      float* x = (pass == 0) ? xd : xs;
      unsigned short* xbf = (pass == 0) ? xbf_d : xbf_s;
      int M = BB * S;
      // fused QKV -> bf16
      launch_gemm_mfma(xbf, wt_bf + WOFF_QKV, bq + l * HD, bk + l * HD, bv + l * HD, HD,
                       nullptr, qkv_bf, M, QKVN, HD, 0, stream);
      attn_mfma<<<dim3(S / AQT, NHEAD, BB), 256, 0, stream>>>(qkv_bf, am, ab_bf, S);
      // O-proj -> fp32
      launch_gemm_mfma(ab_bf, wt_bf + WOFF_O, bo + l * HD, bo + l * HD, bo + l * HD, HD,
                       cbuf, nullptr, M, HD, HD, 0, stream);
      ln_kernel<<<M, 256, 0, stream>>>(cbuf, x, lnag + l * HD, lnab + l * HD, x, xbf);
      // FFN1 + GELU -> bf16
      launch_gemm_mfma(xbf, wt_bf + WOFF_F1, bf1 + l * FFD, bf1 + l * FFD, bf1 + l * FFD, FFD,
                       nullptr, h_bf, M, FFD, HD, 1, stream);
      // FFN2 -> fp32
      launch_gemm_mfma(h_bf, wt_bf + WOFF_F2, bf2 + l * HD, bf2 + l * HD, bf2 + l * HD, HD,
                       cbuf, nullptr, M, HD, FFD, 0, stream);
      ln_kernel<<<M, 256, 0, stream>>>(cbuf, x, lnfg + l * HD, lnfb + l * HD, x, xbf);
    }
  }

  for (int pass = 0; pass < 2; pass++) {
    const float* seq = (pass == 0) ? xd : xs;
    const int* spans = (pass == 0) ? og_spans : llm_spans;
    int S = (pass == 0) ? SDOC : SSUM;
    dots_kernel<<<BB * S / 4, 256, 0, stream>>>(seq, pool_w, dots);
    span_softmax_kernel<<<NSPAN, 256, 0, stream>>>(dots, spans, sidx, probs, S);
    hipMemsetAsync(pooled, 0, NSPAN * HD * sizeof(float), stream);
    wsum_kernel<<<dim3(S / 256, NSPAN), 256, 0, stream>>>(seq, probs, sidx, pooled, S);
    ln_kernel<<<NSPAN, 256, 0, stream>>>(pooled, nullptr, pj_g1, pj_b1, h2, nullptr);
    launch_gemm_f32(h2, pj_W1, pj_c1, g1, NSPAN, HD, HD, 1, stream);
    ln_kernel<<<NSPAN, 256, 0, stream>>>(g1, nullptr, pj_g2, pj_b2, h2, nullptr);
    launch_gemm_f32(h2, pj_W2, pj_c2, proj, NSPAN, PD, HD, 0, stream);
    norm_out_kernel<<<NSPAN, 256, 0, stream>>>(proj, out + pass * NSPAN * PD);
  }
}

// Round 4
// 2747.702 us; speedup vs baseline: 9.9295x; 1.3961x over previous
//
#include <hip/hip_runtime.h>
#include <math.h>

#define BB 2
#define SDOC 2048
#define SSUM 1024
#define HD 768
#define NHEAD 12
#define DHEAD 64
#define FFD 3072
#define NLAYER 6
#define PD 256
#define NSPAN 32
#define WINSZ 256
#define QKVN 2304   // fused QKV output width
#define MTOT 6144   // merged rows: BB*SDOC + BB*SSUM

typedef short s16x8 __attribute__((ext_vector_type(8)));
typedef float f32x4 __attribute__((ext_vector_type(4)));

#define LDS_PTR(p) ((__attribute__((address_space(3))) void*)(p))
#define GLB_PTR(p) ((const __attribute__((address_space(1))) void*)(p))

// ---------------- bf16 helpers (RNE) ----------------
__device__ __forceinline__ unsigned short f2bf(float f) {
  unsigned int u = __builtin_bit_cast(unsigned int, f);
  unsigned int r = (u + 0x7fffu + ((u >> 16) & 1u)) >> 16;
  return (unsigned short)r;
}
__device__ __forceinline__ float bf2f(unsigned short h) {
  unsigned int u = ((unsigned int)h) << 16;
  return __builtin_bit_cast(float, u);
}

// ---------------- block reductions (blockDim == 256) ----------------
__device__ __forceinline__ float block_reduce_sum(float v) {
  __shared__ float sbuf[256];
  sbuf[threadIdx.x] = v;
  __syncthreads();
  for (int i = 128; i > 0; i >>= 1) {
    if ((int)threadIdx.x < i) sbuf[threadIdx.x] += sbuf[threadIdx.x + i];
    __syncthreads();
  }
  float r = sbuf[0];
  __syncthreads();
  return r;
}

__device__ __forceinline__ float block_reduce_max(float v) {
  __shared__ float mbuf[256];
  mbuf[threadIdx.x] = v;
  __syncthreads();
  for (int i = 128; i > 0; i >>= 1) {
    if ((int)threadIdx.x < i) mbuf[threadIdx.x] = fmaxf(mbuf[threadIdx.x], mbuf[threadIdx.x + i]);
    __syncthreads();
  }
  float r = mbuf[0];
  __syncthreads();
  return r;
}

// ---------------- embedding + LayerNorm + bf16 ----------------
__global__ __launch_bounds__(256) void embed_ln_kernel(
    const int* __restrict__ ids, const float* __restrict__ we, const float* __restrict__ pe,
    const float* __restrict__ g, const float* __restrict__ bt, float* __restrict__ xout,
    unsigned short* __restrict__ xb, int S) {
  int row = blockIdx.x;
  int s = row % S;
  int id = ids[row];
  int tid = threadIdx.x;
  float vals[3];
  float sum = 0.f;
#pragma unroll
  for (int i = 0; i < 3; i++) {
    int h = tid + i * 256;
    float t = we[(size_t)id * HD + h] + pe[(size_t)s * HD + h];
    vals[i] = t;
    sum += t;
  }
  float mean = block_reduce_sum(sum) * (1.f / HD);
  float vs = 0.f;
#pragma unroll
  for (int i = 0; i < 3; i++) { float d = vals[i] - mean; vs += d * d; }
  float var = block_reduce_sum(vs) * (1.f / HD);
  float inv = rsqrtf(var + 1e-5f);
#pragma unroll
  for (int i = 0; i < 3; i++) {
    int h = tid + i * 256;
    float v = (vals[i] - mean) * inv * g[h] + bt[h];
    size_t off = (size_t)row * HD + h;
    xout[off] = v;
    xb[off] = f2bf(v);
  }
}

// ---------------- LayerNorm (+optional residual, +optional bf16 out) ----------------
__global__ __launch_bounds__(256) void ln_kernel(
    const float* __restrict__ a, const float* __restrict__ res,
    const float* __restrict__ g, const float* __restrict__ bt, float* __restrict__ out,
    unsigned short* __restrict__ ob) {
  int row = blockIdx.x;
  int tid = threadIdx.x;
  const float* ar = a + (size_t)row * HD;
  const float* rr = res ? res + (size_t)row * HD : nullptr;
  float vals[3];
  float sum = 0.f;
#pragma unroll
  for (int i = 0; i < 3; i++) {
    int h = tid + i * 256;
    float t = ar[h] + (rr ? rr[h] : 0.f);
    vals[i] = t;
    sum += t;
  }
  float mean = block_reduce_sum(sum) * (1.f / HD);
  float vs = 0.f;
#pragma unroll
  for (int i = 0; i < 3; i++) { float d = vals[i] - mean; vs += d * d; }
  float var = block_reduce_sum(vs) * (1.f / HD);
  float inv = rsqrtf(var + 1e-5f);
#pragma unroll
  for (int i = 0; i < 3; i++) {
    int h = tid + i * 256;
    float v = (vals[i] - mean) * inv * g[h] + bt[h];
    size_t off = (size_t)row * HD + h;
    out[off] = v;
    if (ob) ob[off] = f2bf(v);
  }
}

// ---------------- per-layer weight transpose + bf16 cast ----------------
__global__ __launch_bounds__(256) void tc_cast_kernel(
    const float* __restrict__ Wq, const float* __restrict__ Wk, const float* __restrict__ Wv,
    const float* __restrict__ Wo, const float* __restrict__ Wf1, const float* __restrict__ Wf2,
    unsigned short* __restrict__ ob) {
  __shared__ float tile[32][33];
  int z = blockIdx.z;
  const float* W;
  int Kd, Nd;
  size_t off;
  switch (z) {
    case 0: W = Wq;  Kd = HD;  Nd = HD;  off = 0;        break;
    case 1: W = Wk;  Kd = HD;  Nd = HD;  off = 589824;   break;
    case 2: W = Wv;  Kd = HD;  Nd = HD;  off = 1179648;  break;
    case 3: W = Wo;  Kd = HD;  Nd = HD;  off = 1769472;  break;
    case 4: W = Wf1; Kd = HD;  Nd = FFD; off = 2359296;  break;
    default: W = Wf2; Kd = FFD; Nd = HD; off = 4718592;  break;
  }
  int tiles_n = Nd >> 5, tiles_k = Kd >> 5;
  int t = blockIdx.x;
  if (t >= tiles_n * tiles_k) return;
  int tn = t % tiles_n, tk = t / tiles_n;
  int n0 = tn * 32, k0 = tk * 32;
  int tid = threadIdx.x;
  int c = tid & 31, r0 = tid >> 5;
#pragma unroll
  for (int j = 0; j < 4; j++) {
    int r = r0 + j * 8;
    tile[r][c] = W[(size_t)(k0 + r) * Nd + n0 + c];
  }
  __syncthreads();
#pragma unroll
  for (int j = 0; j < 4; j++) {
    int r = r0 + j * 8;  // r = local n, c = local k
    ob[off + (size_t)(n0 + r) * Kd + k0 + c] = f2bf(tile[c][r]);
  }
}

// ---------------- bf16 MFMA GEMM, templated on N-tile (128 or 64) ----------------
// C(M,N) = A(M,K)bf16 @ B^T, B stored (N,K) row-major bf16. Block tile 128 x TN.
// bias segments: col c -> bias[c/seg] ptr b0/b1/b2, offset c%seg.
// act=1: exact GELU. Output fp32 C (if non-null) and/or bf16 Oh (if non-null).
template <int TN>
__global__ __launch_bounds__(256) void gemm_mfma_t(
    const unsigned short* __restrict__ A, const unsigned short* __restrict__ B,
    const float* __restrict__ b0, const float* __restrict__ b1, const float* __restrict__ b2,
    int seg, float* __restrict__ C, unsigned short* __restrict__ Oh,
    int M, int N, int K, int act) {
  constexpr int JT = TN / 32;  // n-fragments per wave
  __shared__ __align__(16) unsigned short sA[128 * 32];
  __shared__ __align__(16) unsigned short sB[TN * 32];
  int tid = threadIdx.x;
  int bm = blockIdx.y * 128, bn = blockIdx.x * TN;
  int wave = tid >> 6, lane = tid & 63;
  int quad = lane >> 4, l16 = lane & 15;
  int wm = (wave >> 1) * 64, wn = (wave & 1) * (TN / 2);

  f32x4 zero = {0.f, 0.f, 0.f, 0.f};
  f32x4 acc[4][JT];
#pragma unroll
  for (int i = 0; i < 4; i++)
#pragma unroll
    for (int j = 0; j < JT; j++) acc[i][j] = zero;

  int e0 = tid * 8;
  int row0 = e0 >> 5;
  int kk0 = e0 & 31;

  for (int k0 = 0; k0 < K; k0 += 32) {
    __syncthreads();
#pragma unroll
    for (int r = 0; r < 2; r++) {
      int row = row0 + r * 64;
      int le = (r * 256 + tid) * 8;
      size_t ga = (size_t)(bm + row) * K + k0 + kk0;
      __builtin_amdgcn_global_load_lds(GLB_PTR(A + ga), LDS_PTR(&sA[le]), 16, 0, 0);
    }
#pragma unroll
    for (int r = 0; r < TN / 64; r++) {
      int row = row0 + r * 64;
      int le = (r * 256 + tid) * 8;
      size_t gb = (size_t)(bn + row) * K + k0 + kk0;
      __builtin_amdgcn_global_load_lds(GLB_PTR(B + gb), LDS_PTR(&sB[le]), 16, 0, 0);
    }
    __syncthreads();
    s16x8 af[4], bf[JT];
#pragma unroll
    for (int i = 0; i < 4; i++)
      af[i] = *(const s16x8*)&sA[(wm + i * 16 + l16) * 32 + quad * 8];
#pragma unroll
    for (int j = 0; j < JT; j++)
      bf[j] = *(const s16x8*)&sB[(wn + j * 16 + l16) * 32 + quad * 8];
#pragma unroll
    for (int i = 0; i < 4; i++)
#pragma unroll
      for (int j = 0; j < JT; j++)
        acc[i][j] = __builtin_amdgcn_mfma_f32_16x16x32_bf16(af[i], bf[j], acc[i][j], 0, 0, 0);
  }

#pragma unroll
  for (int j = 0; j < JT; j++) {
    int col = bn + wn + j * 16 + l16;
    int bidx = col / seg;
    int boff = col - bidx * seg;
    const float* bp = bidx == 0 ? b0 : (bidx == 1 ? b1 : b2);
    float bv = bp[boff];
#pragma unroll
    for (int i = 0; i < 4; i++) {
#pragma unroll
      for (int r = 0; r < 4; r++) {
        int rowg = bm + wm + i * 16 + quad * 4 + r;
        float v = acc[i][j][r] + bv;
        if (act == 1) v = 0.5f * v * (1.f + erff(v * 0.70710678118654752f));
        size_t off = (size_t)rowg * N + col;
        if (C) C[off] = v;
        if (Oh) Oh[off] = f2bf(v);
      }
    }
  }
}

// ---------------- small-M fp32 GEMM (projection head) ----------------
// thread (m = blockIdx.y, n); A-row is wave-uniform (scalar loads), W coalesced over n.
__global__ __launch_bounds__(256) void gemm_small(
    const float* __restrict__ A, const float* __restrict__ W, const float* __restrict__ bias,
    float* __restrict__ C, int N, int K, int act) {
  int n = blockIdx.x * 256 + threadIdx.x;
  int m = blockIdx.y;
  const float* ar = A + (size_t)m * K;
  float a0 = 0.f, a1 = 0.f, a2 = 0.f, a3 = 0.f;
  for (int k = 0; k < K; k += 4) {
    a0 += ar[k] * W[(size_t)k * N + n];
    a1 += ar[k + 1] * W[(size_t)(k + 1) * N + n];
    a2 += ar[k + 2] * W[(size_t)(k + 2) * N + n];
    a3 += ar[k + 3] * W[(size_t)(k + 3) * N + n];
  }
  float v = (a0 + a1) + (a2 + a3) + bias[n];
  if (act == 1) v = 0.5f * v * (1.f + erff(v * 0.70710678118654752f));
  C[(size_t)m * N + n] = v;
}

// ---------------- MFMA sliding-window attention ----------------
#define AQT 64
__global__ __launch_bounds__(256) void attn_mfma(
    const unsigned short* __restrict__ qkv, const int* __restrict__ amask,
    unsigned short* __restrict__ Oh, int S) {
  __shared__ unsigned short Vs[64][72];      // V^T: [d][key], +8 pad
  __shared__ unsigned short Ps[4][16][72];   // per-wave P (query, key), +8 pad
  int b = blockIdx.z, hd = blockIdx.y;
  int p0 = blockIdx.x * AQT;
  int tid = threadIdx.x;
  int wave = tid >> 6, lane = tid & 63;
  int quad = lane >> 4, l16 = lane & 15;
  int kstart = p0 - WINSZ;
  const unsigned short* base = qkv + (size_t)(b * S) * QKVN + hd * DHEAD;

  s16x8 aq[2];
  {
    const unsigned short* qrow = base + (size_t)(p0 + wave * 16 + l16) * QKVN;
    aq[0] = *(const s16x8*)(qrow + quad * 8);
    aq[1] = *(const s16x8*)(qrow + 32 + quad * 8);
  }
  f32x4 o[4];
  f32x4 zero = {0.f, 0.f, 0.f, 0.f};
#pragma unroll
  for (int i = 0; i < 4; i++) o[i] = zero;
  float mi[4] = {-1e30f, -1e30f, -1e30f, -1e30f};
  float li[4] = {0.f, 0.f, 0.f, 0.f};

  for (int t = 0; t < 9; t++) {
    __syncthreads();
    {
      int key = tid & 63, d0 = (tid >> 6) * 16;
      int kp = kstart + t * 64 + key;
      if (kp >= 0 && kp < S) {
        const unsigned short* vrow = base + (size_t)kp * QKVN + 2 * HD + d0;
        s16x8 v0 = *(const s16x8*)(vrow);
        s16x8 v1 = *(const s16x8*)(vrow + 8);
#pragma unroll
        for (int j = 0; j < 8; j++) Vs[d0 + j][key] = (unsigned short)v0[j];
#pragma unroll
        for (int j = 0; j < 8; j++) Vs[d0 + 8 + j][key] = (unsigned short)v1[j];
      } else {
#pragma unroll
        for (int j = 0; j < 16; j++) Vs[d0 + j][key] = 0;
      }
    }
    __syncthreads();

    f32x4 sc[4];
#pragma unroll
    for (int nt = 0; nt < 4; nt++) {
      int kr = kstart + t * 64 + nt * 16 + l16;
      s16x8 bk0 = {0, 0, 0, 0, 0, 0, 0, 0}, bk1 = bk0;
      if (kr >= 0 && kr < S) {
        const unsigned short* krow = base + (size_t)kr * QKVN + HD;
        bk0 = *(const s16x8*)(krow + quad * 8);
        bk1 = *(const s16x8*)(krow + 32 + quad * 8);
      }
      sc[nt] = __builtin_amdgcn_mfma_f32_16x16x32_bf16(aq[0], bk0, zero, 0, 0, 0);
      sc[nt] = __builtin_amdgcn_mfma_f32_16x16x32_bf16(aq[1], bk1, sc[nt], 0, 0, 0);
    }

    float s_val[4][4];
    float tm[4] = {-1e30f, -1e30f, -1e30f, -1e30f};
#pragma unroll
    for (int nt = 0; nt < 4; nt++) {
      int j = t * 64 + nt * 16 + l16;
      int kp = kstart + j;
      int am = (kp >= 0 && kp < S) ? amask[b * S + kp] : 0;
#pragma unroll
      for (int r = 0; r < 4; r++) {
        int ql = wave * 16 + quad * 4 + r;
        bool valid = (am != 0) && (j >= ql) && (j <= ql + 512);
        float v = valid ? sc[nt][r] * 0.125f : -1e9f;
        s_val[nt][r] = v;
        tm[r] = fmaxf(tm[r], v);
      }
    }
#pragma unroll
    for (int m = 1; m < 16; m <<= 1)
#pragma unroll
      for (int r = 0; r < 4; r++) tm[r] = fmaxf(tm[r], __shfl_xor(tm[r], m, 16));

    float alpha[4], rs[4];
#pragma unroll
    for (int r = 0; r < 4; r++) {
      float mn = fmaxf(mi[r], tm[r]);
      alpha[r] = __expf(mi[r] - mn);
      mi[r] = mn;
      rs[r] = 0.f;
    }
#pragma unroll
    for (int nt = 0; nt < 4; nt++)
#pragma unroll
      for (int r = 0; r < 4; r++) {
        float p = __expf(s_val[nt][r] - mi[r]);
        rs[r] += p;
        Ps[wave][quad * 4 + r][nt * 16 + l16] = f2bf(p);
      }
#pragma unroll
    for (int m = 1; m < 16; m <<= 1)
#pragma unroll
      for (int r = 0; r < 4; r++) rs[r] += __shfl_xor(rs[r], m, 16);
#pragma unroll
    for (int r = 0; r < 4; r++) li[r] = li[r] * alpha[r] + rs[r];
#pragma unroll
    for (int dn = 0; dn < 4; dn++)
#pragma unroll
      for (int r = 0; r < 4; r++) o[dn][r] *= alpha[r];

#pragma unroll
    for (int ks = 0; ks < 2; ks++) {
      s16x8 ap = *(const s16x8*)&Ps[wave][l16][ks * 32 + quad * 8];
#pragma unroll
      for (int dn = 0; dn < 4; dn++) {
        s16x8 bv = *(const s16x8*)&Vs[dn * 16 + l16][ks * 32 + quad * 8];
        o[dn] = __builtin_amdgcn_mfma_f32_16x16x32_bf16(ap, bv, o[dn], 0, 0, 0);
      }
    }
  }

#pragma unroll
  for (int r = 0; r < 4; r++) {
    float inv = 1.f / li[r];
    int rowg = b * S + p0 + wave * 16 + quad * 4 + r;
#pragma unroll
    for (int dn = 0; dn < 4; dn++) {
      Oh[(size_t)rowg * HD + hd * DHEAD + dn * 16 + l16] = f2bf(o[dn][r] * inv);
    }
  }
}

// ---------------- pooling path ----------------
__global__ __launch_bounds__(256) void dots_kernel(
    const float* __restrict__ x, const float* __restrict__ pw, float* __restrict__ dots) {
  int row = blockIdx.x * 4 + (threadIdx.x >> 6);
  int lane = threadIdx.x & 63;
  const float* r = x + (size_t)row * HD;
  float s = 0.f;
  for (int i = lane; i < HD; i += 64) s += r[i] * pw[i];
#pragma unroll
  for (int m = 32; m > 0; m >>= 1) s += __shfl_xor(s, m, 64);
  if (lane == 0) dots[row] = fminf(fmaxf(s, -100.f), 100.f);
}

// merged masked softmax: blocks 0..31 = og spans (doc), 32..63 = llm spans (sum)
__global__ __launch_bounds__(256) void span_softmax_kernel(
    const float* __restrict__ dots, const int* __restrict__ og_spans,
    const int* __restrict__ llm_spans, const int* __restrict__ sidx,
    float* __restrict__ probs) {
  int ns = blockIdx.x;
  int pass = ns >> 5;
  int sp = ns & 31;
  int S = pass ? SSUM : SDOC;
  const int* spans = pass ? llm_spans : og_spans;
  int rowbase = pass ? BB * SDOC : 0;
  int bi = sidx[sp];
  const float* dr = dots + rowbase + bi * S;
  int tid = threadIdx.x;
  float mx = -1e30f;
  for (int s = tid; s < S; s += 256) {
    float v = (spans[sp * S + s] == 1) ? dr[s] : -1e9f;
    mx = fmaxf(mx, v);
  }
  mx = block_reduce_max(mx);
  float sum = 0.f;
  for (int s = tid; s < S; s += 256) {
    float v = (spans[sp * S + s] == 1) ? dr[s] : -1e9f;
    float e = __expf(v - mx);
    probs[ns * SDOC + s] = e;
    sum += e;
  }
  sum = block_reduce_sum(sum);
  float inv = 1.f / sum;
  for (int s = tid; s < S; s += 256) probs[ns * SDOC + s] *= inv;
}

// pooled[ns][h] += sum_{s in chunk} probs[ns][s] * seq[bi][s][h]
__global__ __launch_bounds__(256) void wsum_kernel(
    const float* __restrict__ seq, const float* __restrict__ probs,
    const int* __restrict__ sidx, float* __restrict__ pooled, int S, int ns0) {
  __shared__ float ps[256];
  int sp = blockIdx.y;
  int ns = ns0 + sp;
  int s0 = blockIdx.x * 256;
  int bi = sidx[sp];
  int tid = threadIdx.x;
  ps[tid] = probs[ns * SDOC + s0 + tid];
  __syncthreads();
  const float* xb = seq + ((size_t)bi * S + s0) * HD;
  float a0 = 0.f, a1 = 0.f, a2 = 0.f;
  for (int s = 0; s < 256; s++) {
    float p = ps[s];
    const float* row = xb + (size_t)s * HD;
    a0 += p * row[tid];
    a1 += p * row[tid + 256];
    a2 += p * row[tid + 512];
  }
  atomicAdd(&pooled[ns * HD + tid], a0);
  atomicAdd(&pooled[ns * HD + tid + 256], a1);
  atomicAdd(&pooled[ns * HD + tid + 512], a2);
}

// ---------------- final L2 normalize ----------------
__global__ __launch_bounds__(256) void norm_out_kernel(
    const float* __restrict__ proj, float* __restrict__ out) {
  int ns = blockIdx.x;
  float v = proj[ns * PD + threadIdx.x];
  float ss = block_reduce_sum(v * v);
  float n = fmaxf(sqrtf(ss), 1e-12f);
  out[ns * PD + threadIdx.x] = v / n;
}

// ---------------- host side ----------------
static void launch_gemm128(const unsigned short* A, const unsigned short* B,
                           const float* b0, const float* b1, const float* b2, int seg,
                           float* C, unsigned short* Oh, int M, int N, int K, int act,
                           hipStream_t stream) {
  dim3 grid(N / 128, M / 128);
  gemm_mfma_t<128><<<grid, 256, 0, stream>>>(A, B, b0, b1, b2, seg, C, Oh, M, N, K, act);
}
static void launch_gemm64(const unsigned short* A, const unsigned short* B,
                          const float* b0, float* C, unsigned short* Oh,
                          int M, int N, int K, int act, hipStream_t stream) {
  dim3 grid(N / 64, M / 128);
  gemm_mfma_t<64><<<grid, 256, 0, stream>>>(A, B, b0, b0, b0, N, C, Oh, M, N, K, act);
}

// weight segment offsets in the per-layer transposed cache (elements)
#define WOFF_QKV 0
#define WOFF_O   1769472
#define WOFF_F1  2359296
#define WOFF_F2  4718592

extern "C" void kernel_launch(void* const* d_in, const int* in_sizes, int n_in,
                              void* d_out, int out_size, void* d_ws, size_t ws_size,
                              hipStream_t stream) {
  const int* doc_ids   = (const int*)d_in[0];
  const int* doc_am    = (const int*)d_in[1];
  const int* sum_ids   = (const int*)d_in[2];
  const int* sum_am    = (const int*)d_in[3];
  const int* og_spans  = (const int*)d_in[4];
  const int* llm_spans = (const int*)d_in[5];
  const int* sidx      = (const int*)d_in[6];
  const float* word_emb = (const float*)d_in[7];
  const float* pos_emb  = (const float*)d_in[8];
  const float* emb_g = (const float*)d_in[9];
  const float* emb_b = (const float*)d_in[10];
  const float* Wq = (const float*)d_in[11];
  const float* bq = (const float*)d_in[12];
  const float* Wk = (const float*)d_in[13];
  const float* bk = (const float*)d_in[14];
  const float* Wv = (const float*)d_in[15];
  const float* bv = (const float*)d_in[16];
  const float* Wo = (const float*)d_in[17];
  const float* bo = (const float*)d_in[18];
  const float* lnag = (const float*)d_in[19];
  const float* lnab = (const float*)d_in[20];
  const float* Wf1 = (const float*)d_in[21];
  const float* bf1 = (const float*)d_in[22];
  const float* Wf2 = (const float*)d_in[23];
  const float* bf2 = (const float*)d_in[24];
  const float* lnfg = (const float*)d_in[25];
  const float* lnfb = (const float*)d_in[26];
  const float* pool_w = (const float*)d_in[27];
  const float* pj_g1 = (const float*)d_in[28];
  const float* pj_b1 = (const float*)d_in[29];
  const float* pj_W1 = (const float*)d_in[30];
  const float* pj_c1 = (const float*)d_in[31];
  const float* pj_g2 = (const float*)d_in[32];
  const float* pj_b2 = (const float*)d_in[33];
  const float* pj_W2 = (const float*)d_in[34];
  const float* pj_c2 = (const float*)d_in[35];
  float* out = (float*)d_out;

  // ---- workspace layout (~138 MB). doc rows [0,4096), sum rows [4096,6144). ----
  const size_t n_x = (size_t)MTOT * HD;  // 4,718,592
  float* x      = (float*)d_ws;
  float* cbuf   = x + n_x;
  float* pooled = cbuf + n_x;                    // 64*768
  float* g1     = pooled + 2 * NSPAN * HD;
  float* h2     = g1 + 2 * NSPAN * HD;
  float* proj   = h2 + 2 * NSPAN * HD;           // 64*256
  float* dots   = proj + 2 * NSPAN * PD;         // 6144
  float* probs  = dots + MTOT;                   // 64*2048
  unsigned short* xbf    = (unsigned short*)(probs + 2 * NSPAN * SDOC);
  unsigned short* qkv_bf = xbf + n_x;                          // MTOT*2304
  unsigned short* ab_bf  = qkv_bf + (size_t)MTOT * QKVN;       // MTOT*768
  unsigned short* h_bf   = ab_bf + n_x;                        // MTOT*3072
  unsigned short* wt_bf  = h_bf + (size_t)MTOT * FFD;          // 7,077,888

  embed_ln_kernel<<<BB * SDOC, 256, 0, stream>>>(doc_ids, word_emb, pos_emb, emb_g, emb_b,
                                                 x, xbf, SDOC);
  embed_ln_kernel<<<BB * SSUM, 256, 0, stream>>>(sum_ids, word_emb, pos_emb, emb_g, emb_b,
                                                 x + (size_t)BB * SDOC * HD,
                                                 xbf + (size_t)BB * SDOC * HD, SSUM);

  const size_t sum_off = (size_t)BB * SDOC;  // row offset of sum region
  for (int l = 0; l < NLAYER; l++) {
    tc_cast_kernel<<<dim3(2304, 1, 6), 256, 0, stream>>>(
        Wq + (size_t)l * HD * HD, Wk + (size_t)l * HD * HD, Wv + (size_t)l * HD * HD,
        Wo + (size_t)l * HD * HD, Wf1 + (size_t)l * HD * FFD, Wf2 + (size_t)l * FFD * HD,
        wt_bf);
    // fused QKV over merged rows -> bf16
    launch_gemm128(xbf, wt_bf + WOFF_QKV, bq + l * HD, bk + l * HD, bv + l * HD, HD,
                   nullptr, qkv_bf, MTOT, QKVN, HD, 0, stream);
    attn_mfma<<<dim3(SDOC / AQT, NHEAD, BB), 256, 0, stream>>>(qkv_bf, doc_am, ab_bf, SDOC);
    attn_mfma<<<dim3(SSUM / AQT, NHEAD, BB), 256, 0, stream>>>(
        qkv_bf + sum_off * QKVN, sum_am, ab_bf + sum_off * HD, SSUM);
    // O-proj -> fp32
    launch_gemm64(ab_bf, wt_bf + WOFF_O, bo + l * HD, cbuf, nullptr, MTOT, HD, HD, 0, stream);
    ln_kernel<<<MTOT, 256, 0, stream>>>(cbuf, x, lnag + l * HD, lnab + l * HD, x, xbf);
    // FFN1 + GELU -> bf16
    launch_gemm128(xbf, wt_bf + WOFF_F1, bf1 + l * FFD, bf1 + l * FFD, bf1 + l * FFD, FFD,
                   nullptr, h_bf, MTOT, FFD, HD, 1, stream);
    // FFN2 -> fp32
    launch_gemm64(h_bf, wt_bf + WOFF_F2, bf2 + l * HD, cbuf, nullptr, MTOT, HD, FFD, 0, stream);
    ln_kernel<<<MTOT, 256, 0, stream>>>(cbuf, x, lnfg + l * HD, lnfb + l * HD, x, xbf);
  }

  // ---- pooling + projection head (both passes merged; ns 0..31 = human, 32..63 = llm) ----
  dots_kernel<<<MTOT / 4, 256, 0, stream>>>(x, pool_w, dots);
  span_softmax_kernel<<<2 * NSPAN, 256, 0, stream>>>(dots, og_spans, llm_spans, sidx, probs);
  hipMemsetAsync(pooled, 0, 2 * NSPAN * HD * sizeof(float), stream);
  wsum_kernel<<<dim3(SDOC / 256, NSPAN), 256, 0, stream>>>(x, probs, sidx, pooled, SDOC, 0);
  wsum_kernel<<<dim3(SSUM / 256, NSPAN), 256, 0, stream>>>(
      x + sum_off * HD, probs, sidx, pooled, SSUM, NSPAN);
  ln_kernel<<<2 * NSPAN, 256, 0, stream>>>(pooled, nullptr, pj_g1, pj_b1, h2, nullptr);
  gemm_small<<<dim3(HD / 256, 2 * NSPAN), 256, 0, stream>>>(h2, pj_W1, pj_c1, g1, HD, HD, 1);
  ln_kernel<<<2 * NSPAN, 256, 0, stream>>>(g1, nullptr, pj_g2, pj_b2, h2, nullptr);
  gemm_small<<<dim3(PD / 256, 2 * NSPAN), 256, 0, stream>>>(h2, pj_W2, pj_c2, proj, PD, HD, 0);
  norm_out_kernel<<<2 * NSPAN, 256, 0, stream>>>(proj, out);
}

// Round 5
// 2592.401 us; speedup vs baseline: 10.5243x; 1.0599x over previous
//
#include <hip/hip_runtime.h>
#include <math.h>

#define BB 2
#define SDOC 2048
#define SSUM 1024
#define HD 768
#define NHEAD 12
#define DHEAD 64
#define FFD 3072
#define NLAYER 6
#define PD 256
#define NSPAN 32
#define WINSZ 256
#define QKVN 2304   // fused QKV output width
#define MTOT 6144   // merged rows: BB*SDOC + BB*SSUM

typedef short s16x8 __attribute__((ext_vector_type(8)));
typedef float f32x4 __attribute__((ext_vector_type(4)));

#define LDS_PTR(p) ((__attribute__((address_space(3))) void*)(p))
#define GLB_PTR(p) ((const __attribute__((address_space(1))) void*)(p))

// ---------------- bf16 helpers (RNE) ----------------
__device__ __forceinline__ unsigned short f2bf(float f) {
  unsigned int u = __builtin_bit_cast(unsigned int, f);
  unsigned int r = (u + 0x7fffu + ((u >> 16) & 1u)) >> 16;
  return (unsigned short)r;
}
__device__ __forceinline__ float bf2f(unsigned short h) {
  unsigned int u = ((unsigned int)h) << 16;
  return __builtin_bit_cast(float, u);
}

// fast GELU (tanh form via exp). max abs err ~2e-4 — far below bf16 noise.
__device__ __forceinline__ float gelu_f(float x) {
  float t = x * (0.7978845608f + 0.0356774081f * x * x);
  float e = __expf(2.f * t);
  float th = 1.f - 2.f / (e + 1.f);
  return 0.5f * x * (1.f + th);
}

// ---------------- block reductions (blockDim == 256) ----------------
__device__ __forceinline__ float block_reduce_sum(float v) {
  __shared__ float sbuf[256];
  sbuf[threadIdx.x] = v;
  __syncthreads();
  for (int i = 128; i > 0; i >>= 1) {
    if ((int)threadIdx.x < i) sbuf[threadIdx.x] += sbuf[threadIdx.x + i];
    __syncthreads();
  }
  float r = sbuf[0];
  __syncthreads();
  return r;
}

__device__ __forceinline__ float block_reduce_max(float v) {
  __shared__ float mbuf[256];
  mbuf[threadIdx.x] = v;
  __syncthreads();
  for (int i = 128; i > 0; i >>= 1) {
    if ((int)threadIdx.x < i) mbuf[threadIdx.x] = fmaxf(mbuf[threadIdx.x], mbuf[threadIdx.x + i]);
    __syncthreads();
  }
  float r = mbuf[0];
  __syncthreads();
  return r;
}

// ---------------- embedding + LayerNorm + bf16 ----------------
__global__ __launch_bounds__(256) void embed_ln_kernel(
    const int* __restrict__ ids, const float* __restrict__ we, const float* __restrict__ pe,
    const float* __restrict__ g, const float* __restrict__ bt, float* __restrict__ xout,
    unsigned short* __restrict__ xb, int S) {
  int row = blockIdx.x;
  int s = row % S;
  int id = ids[row];
  int tid = threadIdx.x;
  float vals[3];
  float sum = 0.f;
#pragma unroll
  for (int i = 0; i < 3; i++) {
    int h = tid + i * 256;
    float t = we[(size_t)id * HD + h] + pe[(size_t)s * HD + h];
    vals[i] = t;
    sum += t;
  }
  float mean = block_reduce_sum(sum) * (1.f / HD);
  float vs = 0.f;
#pragma unroll
  for (int i = 0; i < 3; i++) { float d = vals[i] - mean; vs += d * d; }
  float var = block_reduce_sum(vs) * (1.f / HD);
  float inv = rsqrtf(var + 1e-5f);
#pragma unroll
  for (int i = 0; i < 3; i++) {
    int h = tid + i * 256;
    float v = (vals[i] - mean) * inv * g[h] + bt[h];
    size_t off = (size_t)row * HD + h;
    xout[off] = v;
    xb[off] = f2bf(v);
  }
}

// ---------------- LayerNorm (+optional residual, +optional bf16 out) ----------------
__global__ __launch_bounds__(256) void ln_kernel(
    const float* __restrict__ a, const float* __restrict__ res,
    const float* __restrict__ g, const float* __restrict__ bt, float* __restrict__ out,
    unsigned short* __restrict__ ob) {
  int row = blockIdx.x;
  int tid = threadIdx.x;
  const float* ar = a + (size_t)row * HD;
  const float* rr = res ? res + (size_t)row * HD : nullptr;
  float vals[3];
  float sum = 0.f;
#pragma unroll
  for (int i = 0; i < 3; i++) {
    int h = tid + i * 256;
    float t = ar[h] + (rr ? rr[h] : 0.f);
    vals[i] = t;
    sum += t;
  }
  float mean = block_reduce_sum(sum) * (1.f / HD);
  float vs = 0.f;
#pragma unroll
  for (int i = 0; i < 3; i++) { float d = vals[i] - mean; vs += d * d; }
  float var = block_reduce_sum(vs) * (1.f / HD);
  float inv = rsqrtf(var + 1e-5f);
#pragma unroll
  for (int i = 0; i < 3; i++) {
    int h = tid + i * 256;
    float v = (vals[i] - mean) * inv * g[h] + bt[h];
    size_t off = (size_t)row * HD + h;
    out[off] = v;
    if (ob) ob[off] = f2bf(v);
  }
}

// ---------------- per-layer weight transpose + bf16 cast ----------------
__global__ __launch_bounds__(256) void tc_cast_kernel(
    const float* __restrict__ Wq, const float* __restrict__ Wk, const float* __restrict__ Wv,
    const float* __restrict__ Wo, const float* __restrict__ Wf1, const float* __restrict__ Wf2,
    unsigned short* __restrict__ ob) {
  __shared__ float tile[32][33];
  int z = blockIdx.z;
  const float* W;
  int Kd, Nd;
  size_t off;
  switch (z) {
    case 0: W = Wq;  Kd = HD;  Nd = HD;  off = 0;        break;
    case 1: W = Wk;  Kd = HD;  Nd = HD;  off = 589824;   break;
    case 2: W = Wv;  Kd = HD;  Nd = HD;  off = 1179648;  break;
    case 3: W = Wo;  Kd = HD;  Nd = HD;  off = 1769472;  break;
    case 4: W = Wf1; Kd = HD;  Nd = FFD; off = 2359296;  break;
    default: W = Wf2; Kd = FFD; Nd = HD; off = 4718592;  break;
  }
  int tiles_n = Nd >> 5, tiles_k = Kd >> 5;
  int t = blockIdx.x;
  if (t >= tiles_n * tiles_k) return;
  int tn = t % tiles_n, tk = t / tiles_n;
  int n0 = tn * 32, k0 = tk * 32;
  int tid = threadIdx.x;
  int c = tid & 31, r0 = tid >> 5;
#pragma unroll
  for (int j = 0; j < 4; j++) {
    int r = r0 + j * 8;
    tile[r][c] = W[(size_t)(k0 + r) * Nd + n0 + c];
  }
  __syncthreads();
#pragma unroll
  for (int j = 0; j < 4; j++) {
    int r = r0 + j * 8;  // r = local n, c = local k
    ob[off + (size_t)(n0 + r) * Kd + k0 + c] = f2bf(tile[c][r]);
  }
}

// ---------------- bf16 MFMA GEMM, double-buffered LDS, templated N-tile ----------------
// C(M,N) = A(M,K)bf16 @ B^T, B stored (N,K) row-major bf16. Block tile 128 x TN.
// bias segments: col c -> bias[c/seg] ptr b0/b1/b2, offset c%seg.
// act=1: fast GELU. Output fp32 C (if non-null) and/or bf16 Oh (if non-null).
template <int TN>
__global__ __launch_bounds__(256) void gemm_mfma_t(
    const unsigned short* __restrict__ A, const unsigned short* __restrict__ B,
    const float* __restrict__ b0, const float* __restrict__ b1, const float* __restrict__ b2,
    int seg, float* __restrict__ C, unsigned short* __restrict__ Oh,
    int M, int N, int K, int act) {
  constexpr int JT = TN / 32;  // n-fragments per wave
  __shared__ __align__(16) unsigned short sA[2][128 * 32];
  __shared__ __align__(16) unsigned short sB[2][TN * 32];
  int tid = threadIdx.x;
  int bm = blockIdx.y * 128, bn = blockIdx.x * TN;
  int wave = tid >> 6, lane = tid & 63;
  int quad = lane >> 4, l16 = lane & 15;
  int wm = (wave >> 1) * 64, wn = (wave & 1) * (TN / 2);

  f32x4 zero = {0.f, 0.f, 0.f, 0.f};
  f32x4 acc[4][JT];
#pragma unroll
  for (int i = 0; i < 4; i++)
#pragma unroll
    for (int j = 0; j < JT; j++) acc[i][j] = zero;

  int e0 = tid * 8;
  int row0 = e0 >> 5;
  int kk0 = e0 & 31;

  auto issue = [&](int kb, int buf) {
    int k0 = kb * 32;
#pragma unroll
    for (int r = 0; r < 2; r++) {
      int row = row0 + r * 64;
      int le = (r * 256 + tid) * 8;
      size_t ga = (size_t)(bm + row) * K + k0 + kk0;
      __builtin_amdgcn_global_load_lds(GLB_PTR(A + ga), LDS_PTR(&sA[buf][le]), 16, 0, 0);
    }
#pragma unroll
    for (int r = 0; r < TN / 64; r++) {
      int row = row0 + r * 64;
      int le = (r * 256 + tid) * 8;
      size_t gb = (size_t)(bn + row) * K + k0 + kk0;
      __builtin_amdgcn_global_load_lds(GLB_PTR(B + gb), LDS_PTR(&sB[buf][le]), 16, 0, 0);
    }
  };

  int nk = K >> 5;
  issue(0, 0);
  for (int kb = 0; kb < nk; kb++) {
    __syncthreads();  // drains loads for buf kb&1; ensures prior reads of other buf done
    if (kb + 1 < nk) issue(kb + 1, (kb + 1) & 1);
    int buf = kb & 1;
    s16x8 af[4], bf[JT];
#pragma unroll
    for (int i = 0; i < 4; i++)
      af[i] = *(const s16x8*)&sA[buf][(wm + i * 16 + l16) * 32 + quad * 8];
#pragma unroll
    for (int j = 0; j < JT; j++)
      bf[j] = *(const s16x8*)&sB[buf][(wn + j * 16 + l16) * 32 + quad * 8];
#pragma unroll
    for (int i = 0; i < 4; i++)
#pragma unroll
      for (int j = 0; j < JT; j++)
        acc[i][j] = __builtin_amdgcn_mfma_f32_16x16x32_bf16(af[i], bf[j], acc[i][j], 0, 0, 0);
  }

#pragma unroll
  for (int j = 0; j < JT; j++) {
    int col = bn + wn + j * 16 + l16;
    int bidx = col / seg;
    int boff = col - bidx * seg;
    const float* bp = bidx == 0 ? b0 : (bidx == 1 ? b1 : b2);
    float bv = bp[boff];
#pragma unroll
    for (int i = 0; i < 4; i++) {
#pragma unroll
      for (int r = 0; r < 4; r++) {
        int rowg = bm + wm + i * 16 + quad * 4 + r;
        float v = acc[i][j][r] + bv;
        if (act == 1) v = gelu_f(v);
        size_t off = (size_t)rowg * N + col;
        if (C) C[off] = v;
        if (Oh) Oh[off] = f2bf(v);
      }
    }
  }
}

// ---------------- small-M fp32 GEMM (projection head) ----------------
__global__ __launch_bounds__(256) void gemm_small(
    const float* __restrict__ A, const float* __restrict__ W, const float* __restrict__ bias,
    float* __restrict__ C, int N, int K, int act) {
  int n = blockIdx.x * 256 + threadIdx.x;
  int m = blockIdx.y;
  const float* ar = A + (size_t)m * K;
  float a0 = 0.f, a1 = 0.f, a2 = 0.f, a3 = 0.f;
  for (int k = 0; k < K; k += 4) {
    a0 += ar[k] * W[(size_t)k * N + n];
    a1 += ar[k + 1] * W[(size_t)(k + 1) * N + n];
    a2 += ar[k + 2] * W[(size_t)(k + 2) * N + n];
    a3 += ar[k + 3] * W[(size_t)(k + 3) * N + n];
  }
  float v = (a0 + a1) + (a2 + a3) + bias[n];
  if (act == 1) v = gelu_f(v);
  C[(size_t)m * N + n] = v;
}

// ---------------- MFMA sliding-window attention ----------------
#define AQT 64
__global__ __launch_bounds__(256) void attn_mfma(
    const unsigned short* __restrict__ qkv, const int* __restrict__ amask,
    unsigned short* __restrict__ Oh, int S) {
  __shared__ unsigned short Vs[64][72];      // V^T: [d][key], +8 pad
  __shared__ unsigned short Ps[4][16][72];   // per-wave P (query, key), +8 pad
  int b = blockIdx.z, hd = blockIdx.y;
  int p0 = blockIdx.x * AQT;
  int tid = threadIdx.x;
  int wave = tid >> 6, lane = tid & 63;
  int quad = lane >> 4, l16 = lane & 15;
  int kstart = p0 - WINSZ;
  const unsigned short* base = qkv + (size_t)(b * S) * QKVN + hd * DHEAD;

  s16x8 aq[2];
  {
    const unsigned short* qrow = base + (size_t)(p0 + wave * 16 + l16) * QKVN;
    aq[0] = *(const s16x8*)(qrow + quad * 8);
    aq[1] = *(const s16x8*)(qrow + 32 + quad * 8);
  }
  f32x4 o[4];
  f32x4 zero = {0.f, 0.f, 0.f, 0.f};
#pragma unroll
  for (int i = 0; i < 4; i++) o[i] = zero;
  float mi[4] = {-1e30f, -1e30f, -1e30f, -1e30f};
  float li[4] = {0.f, 0.f, 0.f, 0.f};

  for (int t = 0; t < 9; t++) {
    __syncthreads();
    {
      int key = tid & 63, d0 = (tid >> 6) * 16;
      int kp = kstart + t * 64 + key;
      if (kp >= 0 && kp < S) {
        const unsigned short* vrow = base + (size_t)kp * QKVN + 2 * HD + d0;
        s16x8 v0 = *(const s16x8*)(vrow);
        s16x8 v1 = *(const s16x8*)(vrow + 8);
#pragma unroll
        for (int j = 0; j < 8; j++) Vs[d0 + j][key] = (unsigned short)v0[j];
#pragma unroll
        for (int j = 0; j < 8; j++) Vs[d0 + 8 + j][key] = (unsigned short)v1[j];
      } else {
#pragma unroll
        for (int j = 0; j < 16; j++) Vs[d0 + j][key] = 0;
      }
    }
    __syncthreads();

    f32x4 sc[4];
#pragma unroll
    for (int nt = 0; nt < 4; nt++) {
      int kr = kstart + t * 64 + nt * 16 + l16;
      s16x8 bk0 = {0, 0, 0, 0, 0, 0, 0, 0}, bk1 = bk0;
      if (kr >= 0 && kr < S) {
        const unsigned short* krow = base + (size_t)kr * QKVN + HD;
        bk0 = *(const s16x8*)(krow + quad * 8);
        bk1 = *(const s16x8*)(krow + 32 + quad * 8);
      }
      sc[nt] = __builtin_amdgcn_mfma_f32_16x16x32_bf16(aq[0], bk0, zero, 0, 0, 0);
      sc[nt] = __builtin_amdgcn_mfma_f32_16x16x32_bf16(aq[1], bk1, sc[nt], 0, 0, 0);
    }

    float s_val[4][4];
    float tm[4] = {-1e30f, -1e30f, -1e30f, -1e30f};
#pragma unroll
    for (int nt = 0; nt < 4; nt++) {
      int j = t * 64 + nt * 16 + l16;
      int kp = kstart + j;
      int am = (kp >= 0 && kp < S) ? amask[b * S + kp] : 0;
#pragma unroll
      for (int r = 0; r < 4; r++) {
        int ql = wave * 16 + quad * 4 + r;
        bool valid = (am != 0) && (j >= ql) && (j <= ql + 512);
        float v = valid ? sc[nt][r] * 0.125f : -1e9f;
        s_val[nt][r] = v;
        tm[r] = fmaxf(tm[r], v);
      }
    }
#pragma unroll
    for (int m = 1; m < 16; m <<= 1)
#pragma unroll
      for (int r = 0; r < 4; r++) tm[r] = fmaxf(tm[r], __shfl_xor(tm[r], m, 16));

    float alpha[4], rs[4];
#pragma unroll
    for (int r = 0; r < 4; r++) {
      float mn = fmaxf(mi[r], tm[r]);
      alpha[r] = __expf(mi[r] - mn);
      mi[r] = mn;
      rs[r] = 0.f;
    }
#pragma unroll
    for (int nt = 0; nt < 4; nt++)
#pragma unroll
      for (int r = 0; r < 4; r++) {
        float p = __expf(s_val[nt][r] - mi[r]);
        rs[r] += p;
        Ps[wave][quad * 4 + r][nt * 16 + l16] = f2bf(p);
      }
#pragma unroll
    for (int m = 1; m < 16; m <<= 1)
#pragma unroll
      for (int r = 0; r < 4; r++) rs[r] += __shfl_xor(rs[r], m, 16);
#pragma unroll
    for (int r = 0; r < 4; r++) li[r] = li[r] * alpha[r] + rs[r];
#pragma unroll
    for (int dn = 0; dn < 4; dn++)
#pragma unroll
      for (int r = 0; r < 4; r++) o[dn][r] *= alpha[r];

#pragma unroll
    for (int ks = 0; ks < 2; ks++) {
      s16x8 ap = *(const s16x8*)&Ps[wave][l16][ks * 32 + quad * 8];
#pragma unroll
      for (int dn = 0; dn < 4; dn++) {
        s16x8 bv = *(const s16x8*)&Vs[dn * 16 + l16][ks * 32 + quad * 8];
        o[dn] = __builtin_amdgcn_mfma_f32_16x16x32_bf16(ap, bv, o[dn], 0, 0, 0);
      }
    }
  }

#pragma unroll
  for (int r = 0; r < 4; r++) {
    float inv = 1.f / li[r];
    int rowg = b * S + p0 + wave * 16 + quad * 4 + r;
#pragma unroll
    for (int dn = 0; dn < 4; dn++) {
      Oh[(size_t)rowg * HD + hd * DHEAD + dn * 16 + l16] = f2bf(o[dn][r] * inv);
    }
  }
}

// ---------------- pooling path ----------------
__global__ __launch_bounds__(256) void dots_kernel(
    const float* __restrict__ x, const float* __restrict__ pw, float* __restrict__ dots) {
  int row = blockIdx.x * 4 + (threadIdx.x >> 6);
  int lane = threadIdx.x & 63;
  const float* r = x + (size_t)row * HD;
  float s = 0.f;
  for (int i = lane; i < HD; i += 64) s += r[i] * pw[i];
#pragma unroll
  for (int m = 32; m > 0; m >>= 1) s += __shfl_xor(s, m, 64);
  if (lane == 0) dots[row] = fminf(fmaxf(s, -100.f), 100.f);
}

// merged masked softmax: blocks 0..31 = og spans (doc), 32..63 = llm spans (sum)
__global__ __launch_bounds__(256) void span_softmax_kernel(
    const float* __restrict__ dots, const int* __restrict__ og_spans,
    const int* __restrict__ llm_spans, const int* __restrict__ sidx,
    float* __restrict__ probs) {
  int ns = blockIdx.x;
  int pass = ns >> 5;
  int sp = ns & 31;
  int S = pass ? SSUM : SDOC;
  const int* spans = pass ? llm_spans : og_spans;
  int rowbase = pass ? BB * SDOC : 0;
  int bi = sidx[sp];
  const float* dr = dots + rowbase + bi * S;
  int tid = threadIdx.x;
  float mx = -1e30f;
  for (int s = tid; s < S; s += 256) {
    float v = (spans[sp * S + s] == 1) ? dr[s] : -1e9f;
    mx = fmaxf(mx, v);
  }
  mx = block_reduce_max(mx);
  float sum = 0.f;
  for (int s = tid; s < S; s += 256) {
    float v = (spans[sp * S + s] == 1) ? dr[s] : -1e9f;
    float e = __expf(v - mx);
    probs[ns * SDOC + s] = e;
    sum += e;
  }
  sum = block_reduce_sum(sum);
  float inv = 1.f / sum;
  for (int s = tid; s < S; s += 256) probs[ns * SDOC + s] *= inv;
}

// pooled[ns][h] += sum_{s in chunk} probs[ns][s] * seq[bi][s][h]
__global__ __launch_bounds__(256) void wsum_kernel(
    const float* __restrict__ seq, const float* __restrict__ probs,
    const int* __restrict__ sidx, float* __restrict__ pooled, int S, int ns0) {
  __shared__ float ps[256];
  int sp = blockIdx.y;
  int ns = ns0 + sp;
  int s0 = blockIdx.x * 256;
  int bi = sidx[sp];
  int tid = threadIdx.x;
  ps[tid] = probs[ns * SDOC + s0 + tid];
  __syncthreads();
  const float* xb = seq + ((size_t)bi * S + s0) * HD;
  float a0 = 0.f, a1 = 0.f, a2 = 0.f;
  for (int s = 0; s < 256; s++) {
    float p = ps[s];
    const float* row = xb + (size_t)s * HD;
    a0 += p * row[tid];
    a1 += p * row[tid + 256];
    a2 += p * row[tid + 512];
  }
  atomicAdd(&pooled[ns * HD + tid], a0);
  atomicAdd(&pooled[ns * HD + tid + 256], a1);
  atomicAdd(&pooled[ns * HD + tid + 512], a2);
}

// ---------------- final L2 normalize ----------------
__global__ __launch_bounds__(256) void norm_out_kernel(
    const float* __restrict__ proj, float* __restrict__ out) {
  int ns = blockIdx.x;
  float v = proj[ns * PD + threadIdx.x];
  float ss = block_reduce_sum(v * v);
  float n = fmaxf(sqrtf(ss), 1e-12f);
  out[ns * PD + threadIdx.x] = v / n;
}

// ---------------- host side ----------------
static void launch_gemm128(const unsigned short* A, const unsigned short* B,
                           const float* b0, const float* b1, const float* b2, int seg,
                           float* C, unsigned short* Oh, int M, int N, int K, int act,
                           hipStream_t stream) {
  dim3 grid(N / 128, M / 128);
  gemm_mfma_t<128><<<grid, 256, 0, stream>>>(A, B, b0, b1, b2, seg, C, Oh, M, N, K, act);
}
static void launch_gemm64(const unsigned short* A, const unsigned short* B,
                          const float* b0, float* C, unsigned short* Oh,
                          int M, int N, int K, int act, hipStream_t stream) {
  dim3 grid(N / 64, M / 128);
  gemm_mfma_t<64><<<grid, 256, 0, stream>>>(A, B, b0, b0, b0, N, C, Oh, M, N, K, act);
}

// weight segment offsets in the per-layer transposed cache (elements)
#define WOFF_QKV 0
#define WOFF_O   1769472
#define WOFF_F1  2359296
#define WOFF_F2  4718592

extern "C" void kernel_launch(void* const* d_in, const int* in_sizes, int n_in,
                              void* d_out, int out_size, void* d_ws, size_t ws_size,
                              hipStream_t stream) {
  const int* doc_ids   = (const int*)d_in[0];
  const int* doc_am    = (const int*)d_in[1];
  const int* sum_ids   = (const int*)d_in[2];
  const int* sum_am    = (const int*)d_in[3];
  const int* og_spans  = (const int*)d_in[4];
  const int* llm_spans = (const int*)d_in[5];
  const int* sidx      = (const int*)d_in[6];
  const float* word_emb = (const float*)d_in[7];
  const float* pos_emb  = (const float*)d_in[8];
  const float* emb_g = (const float*)d_in[9];
  const float* emb_b = (const float*)d_in[10];
  const float* Wq = (const float*)d_in[11];
  const float* bq = (const float*)d_in[12];
  const float* Wk = (const float*)d_in[13];
  const float* bk = (const float*)d_in[14];
  const float* Wv = (const float*)d_in[15];
  const float* bv = (const float*)d_in[16];
  const float* Wo = (const float*)d_in[17];
  const float* bo = (const float*)d_in[18];
  const float* lnag = (const float*)d_in[19];
  const float* lnab = (const float*)d_in[20];
  const float* Wf1 = (const float*)d_in[21];
  const float* bf1 = (const float*)d_in[22];
  const float* Wf2 = (const float*)d_in[23];
  const float* bf2 = (const float*)d_in[24];
  const float* lnfg = (const float*)d_in[25];
  const float* lnfb = (const float*)d_in[26];
  const float* pool_w = (const float*)d_in[27];
  const float* pj_g1 = (const float*)d_in[28];
  const float* pj_b1 = (const float*)d_in[29];
  const float* pj_W1 = (const float*)d_in[30];
  const float* pj_c1 = (const float*)d_in[31];
  const float* pj_g2 = (const float*)d_in[32];
  const float* pj_b2 = (const float*)d_in[33];
  const float* pj_W2 = (const float*)d_in[34];
  const float* pj_c2 = (const float*)d_in[35];
  float* out = (float*)d_out;

  // ---- workspace layout (~138 MB). doc rows [0,4096), sum rows [4096,6144). ----
  const size_t n_x = (size_t)MTOT * HD;  // 4,718,592
  float* x      = (float*)d_ws;
  float* cbuf   = x + n_x;
  float* pooled = cbuf + n_x;                    // 64*768
  float* g1     = pooled + 2 * NSPAN * HD;
  float* h2     = g1 + 2 * NSPAN * HD;
  float* proj   = h2 + 2 * NSPAN * HD;           // 64*256
  float* dots   = proj + 2 * NSPAN * PD;         // 6144
  float* probs  = dots + MTOT;                   // 64*2048
  unsigned short* xbf    = (unsigned short*)(probs + 2 * NSPAN * SDOC);
  unsigned short* qkv_bf = xbf + n_x;                          // MTOT*2304
  unsigned short* ab_bf  = qkv_bf + (size_t)MTOT * QKVN;       // MTOT*768
  unsigned short* h_bf   = ab_bf + n_x;                        // MTOT*3072
  unsigned short* wt_bf  = h_bf + (size_t)MTOT * FFD;          // 7,077,888

  embed_ln_kernel<<<BB * SDOC, 256, 0, stream>>>(doc_ids, word_emb, pos_emb, emb_g, emb_b,
                                                 x, xbf, SDOC);
  embed_ln_kernel<<<BB * SSUM, 256, 0, stream>>>(sum_ids, word_emb, pos_emb, emb_g, emb_b,
                                                 x + (size_t)BB * SDOC * HD,
                                                 xbf + (size_t)BB * SDOC * HD, SSUM);

  const size_t sum_off = (size_t)BB * SDOC;  // row offset of sum region
  for (int l = 0; l < NLAYER; l++) {
    tc_cast_kernel<<<dim3(2304, 1, 6), 256, 0, stream>>>(
        Wq + (size_t)l * HD * HD, Wk + (size_t)l * HD * HD, Wv + (size_t)l * HD * HD,
        Wo + (size_t)l * HD * HD, Wf1 + (size_t)l * HD * FFD, Wf2 + (size_t)l * FFD * HD,
        wt_bf);
    // fused QKV over merged rows -> bf16
    launch_gemm128(xbf, wt_bf + WOFF_QKV, bq + l * HD, bk + l * HD, bv + l * HD, HD,
                   nullptr, qkv_bf, MTOT, QKVN, HD, 0, stream);
    attn_mfma<<<dim3(SDOC / AQT, NHEAD, BB), 256, 0, stream>>>(qkv_bf, doc_am, ab_bf, SDOC);
    attn_mfma<<<dim3(SSUM / AQT, NHEAD, BB), 256, 0, stream>>>(
        qkv_bf + sum_off * QKVN, sum_am, ab_bf + sum_off * HD, SSUM);
    // O-proj -> fp32
    launch_gemm64(ab_bf, wt_bf + WOFF_O, bo + l * HD, cbuf, nullptr, MTOT, HD, HD, 0, stream);
    ln_kernel<<<MTOT, 256, 0, stream>>>(cbuf, x, lnag + l * HD, lnab + l * HD, x, xbf);
    // FFN1 + GELU -> bf16
    launch_gemm128(xbf, wt_bf + WOFF_F1, bf1 + l * FFD, bf1 + l * FFD, bf1 + l * FFD, FFD,
                   nullptr, h_bf, MTOT, FFD, HD, 1, stream);
    // FFN2 -> fp32
    launch_gemm64(h_bf, wt_bf + WOFF_F2, bf2 + l * HD, cbuf, nullptr, MTOT, HD, FFD, 0, stream);
    ln_kernel<<<MTOT, 256, 0, stream>>>(cbuf, x, lnfg + l * HD, lnfb + l * HD, x, xbf);
  }

  // ---- pooling + projection head (both passes merged; ns 0..31 = human, 32..63 = llm) ----
  dots_kernel<<<MTOT / 4, 256, 0, stream>>>(x, pool_w, dots);
  span_softmax_kernel<<<2 * NSPAN, 256, 0, stream>>>(dots, og_spans, llm_spans, sidx, probs);
  hipMemsetAsync(pooled, 0, 2 * NSPAN * HD * sizeof(float), stream);
  wsum_kernel<<<dim3(SDOC / 256, NSPAN), 256, 0, stream>>>(x, probs, sidx, pooled, SDOC, 0);
  wsum_kernel<<<dim3(SSUM / 256, NSPAN), 256, 0, stream>>>(
      x + sum_off * HD, probs, sidx, pooled, SSUM, NSPAN);
  ln_kernel<<<2 * NSPAN, 256, 0, stream>>>(pooled, nullptr, pj_g1, pj_b1, h2, nullptr);
  gemm_small<<<dim3(HD / 256, 2 * NSPAN), 256, 0, stream>>>(h2, pj_W1, pj_c1, g1, HD, HD, 1);
  ln_kernel<<<2 * NSPAN, 256, 0, stream>>>(g1, nullptr, pj_g2, pj_b2, h2, nullptr);
  gemm_small<<<dim3(PD / 256, 2 * NSPAN), 256, 0, stream>>>(h2, pj_W2, pj_c2, proj, PD, HD, 0);
  norm_out_kernel<<<2 * NSPAN, 256, 0, stream>>>(proj, out);
}